// Round 2
// baseline (336.782 us; speedup 1.0000x reference)
//
#include <hip/hip_runtime.h>
#include <math.h>

#define TPB 256
#define LW  1000
#define CSTR 1124   // f1e per-channel stride (1000 + 2*60 halo + 4 pad)

// ---- LDS layout (float offsets) ----
#define OFF_WFE   0        // 1120: wf reflect-ext, orig [-100,1020), core at +100
#define OFF_CUME  1120     // 1120: cumsum reflect-ext, core at +100
#define OFF_DSE   2240     // 1120: div_x_smd reflect-ext, core at +100
#define OFF_F1E   3360     // 3372 (+pad): features1 (UNNORMALIZED), core at +60, stride 1124
#define OFF_SCAND 3360     // alias: 512 floats = 256 doubles (wf fp64 scan)
#define OFF_C     3872     // alias: 1000 floats (d1 cumsum)
#define OFF_RED   6740     // 12 reduction scratch
#define SMEM_F    6752     // 27,008 B -> 6 blocks/CU
// phase-2 aliases of [0,3360) (staging dead after fused conv):
#define OFF_KC    0        // 372 composed kernel (scaled by 1/S per cin)
#define OFF_WS2   376      // 1080 = 15*3 rows, stride 24 (21 used, scaled by 1/S per cin)
#define OFF_F2V   1456     // 1560 = 15*104: phantom f2; left at [0,50), right at [52,102)
#define OFF_PART  0        // 500 (alias KC/WS2 head; written after their last use)

__device__ __forceinline__ float4 ld4(const float* p) { return *(const float4*)p; }

__device__ __forceinline__ float blk_red_max(float v, float* red) {
  #pragma unroll
  for (int o = 32; o > 0; o >>= 1) v = fmaxf(v, __shfl_xor(v, o, 64));
  const int w = threadIdx.x >> 6;
  if ((threadIdx.x & 63) == 0) red[w] = v;
  __syncthreads();
  float r = fmaxf(fmaxf(red[0], red[1]), fmaxf(red[2], red[3]));
  __syncthreads();
  return r;
}

__device__ __forceinline__ float blk_red_sum(float v, float* red) {
  #pragma unroll
  for (int o = 32; o > 0; o >>= 1) v += __shfl_xor(v, o, 64);
  const int w = threadIdx.x >> 6;
  if ((threadIdx.x & 63) == 0) red[w] = v;
  __syncthreads();
  float r = red[0] + red[1] + red[2] + red[3];
  __syncthreads();
  return r;
}

// fused triple block-sum: one barrier pair instead of three
__device__ __forceinline__ void blk_red_sum3(float& a, float& b, float& c, float* red) {
  #pragma unroll
  for (int o = 32; o > 0; o >>= 1) {
    a += __shfl_xor(a, o, 64);
    b += __shfl_xor(b, o, 64);
    c += __shfl_xor(c, o, 64);
  }
  const int w = threadIdx.x >> 6;
  if ((threadIdx.x & 63) == 0) { red[w] = a; red[4 + w] = b; red[8 + w] = c; }
  __syncthreads();
  a = red[0] + red[1] + red[2]  + red[3];
  b = red[4] + red[5] + red[6]  + red[7];
  c = red[8] + red[9] + red[10] + red[11];
  __syncthreads();
}

__device__ __forceinline__ int refl(int j) {
  return j < 0 ? -j : (j >= LW ? 2 * LW - 2 - j : j);
}

// phantom-f2 inner: 21-tap conv, 4 outputs, sliding b128 window.
// OFF0 is the compile-time misalignment (0 for left side, 2 for right side).
template<int OFF0>
__device__ __forceinline__ void f2v_accum(const float* xr, const float* wr, float acc[4]) {
  float xw[12];
  *(float4*)xw       = ld4(xr);
  *(float4*)(xw + 4) = ld4(xr + 4);
  *(float4*)(xw + 8) = ld4(xr + 8);
  #pragma unroll
  for (int jb = 0; jb < 20; jb += 4) {
    float4 w4 = ld4(wr + jb);
    const float wv[4] = {w4.x, w4.y, w4.z, w4.w};
    #pragma unroll
    for (int kk = 0; kk < 4; ++kk)
      #pragma unroll
      for (int o = 0; o < 4; ++o)
        acc[o] = fmaf(wv[kk], xw[OFF0 + kk + o], acc[o]);
    #pragma unroll
    for (int j = 0; j < 8; ++j) xw[j] = xw[j + 4];
    *(float4*)(xw + 8) = ld4(xr + jb + 12);
  }
  const float w20 = wr[20];
  #pragma unroll
  for (int o = 0; o < 4; ++o) acc[o] = fmaf(w20, xw[OFF0 + o], acc[o]);
}

// P[m][cin][k] = sum_q conv(wcb[q,:,m], wsub[3q+m][cin])[k], k in [0,121)
// P[1090] = max(SPE); P[1091+k] = wca[k] - sum(wca)*wrl[k] (wrl zero-extended)
extern "C" __global__ void prep_kernel(const float* __restrict__ wsub_g,
                                       const float* __restrict__ wcb_g,
                                       const float* __restrict__ wca_g,
                                       const float* __restrict__ spe_g,
                                       const float* __restrict__ wrl_g,
                                       float* __restrict__ P) {
  __shared__ float sred[4];
  __shared__ float s_swca;
  const int task = blockIdx.x * blockDim.x + threadIdx.x;
  if (task < 1089) {
    const int m = task / 363;
    const int r = task - m * 363;
    const int cin = r / 121;
    const int k = r - cin * 121;
    float acc = 0.f;
    for (int q = 0; q < 5; ++q) {
      const int ch = 3 * q + m;
      const float* ws = wsub_g + (ch * 3 + cin) * 21;
      #pragma unroll
      for (int j = 0; j < 21; ++j) {
        const int a = k - j;
        if (a >= 0 && a <= 100) acc = fmaf(ws[j], wcb_g[q * 303 + a * 3 + m], acc);
      }
    }
    P[task] = acc;
  }
  if (blockIdx.x == 4) {   // SPE max + combined cum/roll kernel
    float mx = -INFINITY;
    for (int t = threadIdx.x; t < LW; t += TPB) mx = fmaxf(mx, spe_g[t]);
    #pragma unroll
    for (int o = 32; o > 0; o >>= 1) mx = fmaxf(mx, __shfl_xor(mx, o, 64));
    if ((threadIdx.x & 63) == 0) sred[threadIdx.x >> 6] = mx;
    if (threadIdx.x == 0) {
      float s = 0.f;
      for (int k = 0; k < 121; ++k) s += wca_g[k];
      s_swca = s;
    }
    __syncthreads();
    if (threadIdx.x == 0)
      P[1090] = fmaxf(fmaxf(sred[0], sred[1]), fmaxf(sred[2], sred[3]));
    if (threadIdx.x < 121) {
      const int k = threadIdx.x;
      float w = 0.f;
      if (k < 101) w = wrl_g[k];
      P[1091 + k] = wca_g[k] - s_swca * w;
    }
  }
}

extern "C" __global__ void __launch_bounds__(TPB, 6)
spot_kernel(const float* __restrict__ wf_g,  const float* __restrict__ mask_g,
            const float* __restrict__ spe_g, const float* __restrict__ wca_g,
            const float* __restrict__ wx_g,  const float* __restrict__ wdv_g,
            const float* __restrict__ wrl_g, const float* __restrict__ wsub_g,
            const float* __restrict__ wcb_g, const float* __restrict__ wp_g,
            const float* __restrict__ P_g,   float* __restrict__ out_g)
{
  __shared__ __align__(16) float sm[SMEM_F];
  const int tid = threadIdx.x;
  const int b = blockIdx.x;
  const float* wf = wf_g + (size_t)b * LW;
  float* red = sm + OFF_RED;
  const int t0 = 4 * tid;

  // ---------------- phase 0: staging, maxima, wf fp64 scan partials ----------
  // (round-0 verified form: scalar stride-1 LDS writes, conflict-free)
  for (int i = tid; i < 1120; i += TPB) sm[OFF_WFE + i] = wf[refl(i - 100)];
  double* scand = (double*)(sm + OFF_SCAND);
  double l0 = 0, l1 = 0, l2 = 0, l3 = 0;
  float hmx = -INFINITY;
  if (tid < 250) {
    float4 wv4 = ld4(wf + t0);
    hmx = fmaxf(fmaxf(wv4.x, wv4.y), fmaxf(wv4.z, wv4.w));
    l0 = (double)wv4.x;
    l1 = l0 + (double)wv4.y;
    l2 = l1 + (double)wv4.z;
    l3 = l2 + (double)wv4.w;
  }
  scand[tid] = l3;
  hmx = blk_red_max(hmx, red);   // barriers publish wfe/scand

  // per-sample 3-way mixing weights W
  const float smx = P_g[1090];
  const float h = hmx / smx;
  float a0 = -fmaxf(h - wp_g[0], 0.f);
  float a1 = -fmaxf(h - wp_g[1], 0.f);
  float a2 = -fmaxf(h - wp_g[2], 0.f);
  float am = fmaxf(a0, fmaxf(a1, a2));
  float e0 = expf(a0 - am), e1 = expf(a1 - am), e2 = expf(a2 - am);
  float es = e0 + e1 + e2;
  float Wv[3] = { e0 / es, e1 / es, e2 / es };

  // ---------------- wf cumsum: fp64 block scan ----------------
  if (tid < 64) {
    double s0 = scand[4 * tid], s1 = scand[4 * tid + 1];
    double s2 = scand[4 * tid + 2], s3 = scand[4 * tid + 3];
    double tot = s0 + s1 + s2 + s3;
    double inc = tot;
    #pragma unroll
    for (int o = 1; o < 64; o <<= 1) {
      double n = __shfl_up(inc, o, 64);
      if ((tid & 63) >= o) inc += n;
    }
    double ex = inc - tot;
    scand[4 * tid]     = ex;
    scand[4 * tid + 1] = ex + s0;
    scand[4 * tid + 2] = ex + s0 + s1;
    scand[4 * tid + 3] = ex + s0 + s1 + s2;
  }
  __syncthreads();                                   // B1
  if (tid < 250) {
    double base = scand[tid];
    float4 cv = { (float)(base + l0), (float)(base + l1),
                  (float)(base + l2), (float)(base + l3) };
    *(float4*)(sm + OFF_CUME + 100 + t0) = cv;
  }
  // d1 (9-tap derivative, zero-padded) in registers + fp32 scan partials
  const float dker[9] = {1.f/280.f, -4.f/105.f, 0.2f, -0.8f, 0.f, 0.8f, -0.2f, 4.f/105.f, -1.f/280.f};
  float dv0 = 0, dv1 = 0, dv2 = 0, dv3 = 0;
  if (tid >= 1 && tid <= 248) {          // safe interior: orig window [t0-4, t0+7]
    float xw[12];
    const float* xr = sm + OFF_WFE + t0 + 96;
    *(float4*)xw = ld4(xr); *(float4*)(xw+4) = ld4(xr+4); *(float4*)(xw+8) = ld4(xr+8);
    float d[4];
    #pragma unroll
    for (int j = 0; j < 4; ++j) {
      float a = 0.f;
      #pragma unroll
      for (int k = 0; k < 9; ++k) {
        if (k == 4) continue;
        a = fmaf(dker[k], xw[j + k], a);
      }
      d[j] = a;
    }
    dv0 = d[0]; dv1 = d[1]; dv2 = d[2]; dv3 = d[3];
  } else if (tid == 0 || tid == 249) {   // edges: zero-padded scalar path
    float d[4];
    #pragma unroll
    for (int j = 0; j < 4; ++j) {
      float a = 0.f;
      for (int k = 0; k < 9; ++k) {
        if (k == 4) continue;
        const int o = t0 + j - 4 + k;
        if (o >= 0 && o < LW) a = fmaf(dker[k], sm[OFF_WFE + 100 + o], a);
      }
      d[j] = a;
    }
    dv0 = d[0]; dv1 = d[1]; dv2 = d[2]; dv3 = d[3];
  }
  // fp32 scan of d1
  {
    const float s0 = dv0, s1 = s0 + dv1, s2 = s1 + dv2, s3 = s2 + dv3;
    float inc = s3;
    const int lane = tid & 63;
    #pragma unroll
    for (int o = 1; o < 64; o <<= 1) {
      float n = __shfl_up(inc, o, 64);
      if (lane >= o) inc += n;
    }
    float* redw = red + 4;
    if (lane == 63) redw[tid >> 6] = inc;
    __syncthreads();                                 // B2 (publishes CUME core too)
    float base = 0.f;
    for (int w = 0; w < (tid >> 6); ++w) base += redw[w];
    if (tid < 250) {
      const float ex = base + inc - s3;
      float4 cv = { ex + s0, ex + s1, ex + s2, ex + s3 };
      *(float4*)(sm + OFF_C + t0) = cv;
    }
  }
  __syncthreads();                                   // B3
  // dse core = (C[t+25]-C[t-26])/51 ; cume halos (round-0 form)
  for (int t = tid; t < LW; t += TPB) {
    const float hi = sm[OFF_C + (t + 25 > 999 ? 999 : t + 25)];
    const float lo = (t >= 26) ? sm[OFF_C + t - 26] : 0.f;
    sm[OFF_DSE + 100 + t] = (hi - lo) * (1.f / 51.f);
  }
  for (int i = tid; i < 120; i += TPB) {
    if (i < 100) sm[OFF_CUME + i] = sm[OFF_CUME + 200 - i];
    else         sm[OFF_CUME + 1000 + i] = sm[OFF_CUME + 2198 - (1000 + i)];
  }
  __syncthreads();                                   // B4
  for (int i = tid; i < 120; i += TPB) {             // dse halos reflect (round-0 form)
    if (i < 100) sm[OFF_DSE + i] = sm[OFF_DSE + 200 - i];
    else         sm[OFF_DSE + 1000 + i] = sm[OFF_DSE + 2198 - (1000 + i)];
  }
  __syncthreads();                                   // B5

  // ------- fused reflect convs -> features1 (3 kernels: kCB, wx, wdv) -------
  float lsC = 0.f, lsX = 0.f, lsD = 0.f;
  if (tid < 250) {
    const float* ce = sm + OFF_CUME + t0;
    const float* we = sm + OFF_WFE + t0;
    const float* de = sm + OFF_DSE + t0;
    const float* kcb = P_g + 1091;                   // wca - sum(wca)*wrl, precomposed
    float cw_[8], ww_[8], dw_[8];
    *(float4*)cw_ = ld4(ce); *(float4*)(cw_ + 4) = ld4(ce + 4);
    *(float4*)ww_ = ld4(we); *(float4*)(ww_ + 4) = ld4(we + 4);
    *(float4*)dw_ = ld4(de); *(float4*)(dw_ + 4) = ld4(de + 4);
    float aC[4] = {0,0,0,0}, aX[4] = {0,0,0,0}, aD[4] = {0,0,0,0};
    for (int g = 0; g < 116; g += 4) {               // taps 0..115
      #pragma unroll
      for (int kk = 0; kk < 4; ++kk) {
        const int k = g + kk;
        const float wc = kcb[k], wxk = wx_g[k], wdk = wdv_g[k];
        #pragma unroll
        for (int j = 0; j < 4; ++j) {
          aC[j] = fmaf(wc,  cw_[kk + j], aC[j]);
          aX[j] = fmaf(wxk, ww_[kk + j], aX[j]);
          aD[j] = fmaf(wdk, dw_[kk + j], aD[j]);
        }
      }
      #pragma unroll
      for (int j = 0; j < 4; ++j) { cw_[j] = cw_[j+4]; ww_[j] = ww_[j+4]; dw_[j] = dw_[j+4]; }
      *(float4*)(cw_ + 4) = ld4(ce + g + 8);
      *(float4*)(ww_ + 4) = ld4(we + g + 8);
      *(float4*)(dw_ + 4) = ld4(de + g + 8);
    }
    #pragma unroll
    for (int kk = 0; kk < 5; ++kk) {                 // taps 116..120 from window
      const int k = 116 + kk;
      const float wc = kcb[k], wxk = wx_g[k], wdk = wdv_g[k];
      #pragma unroll
      for (int j = 0; j < 4; ++j) {
        aC[j] = fmaf(wc,  cw_[kk + j], aC[j]);
        aX[j] = fmaf(wxk, ww_[kk + j], aX[j]);
        aD[j] = fmaf(wdk, dw_[kk + j], aD[j]);
      }
    }
    float4 vC, vX, vD;
    float* pC = (float*)&vC; float* pX = (float*)&vX; float* pD = (float*)&vD;
    #pragma unroll
    for (int j = 0; j < 4; ++j) {
      float fc = fmaxf(aC[j], 0.f);
      float fx = fmaxf(aX[j], 0.f);
      float fd = fmaxf(aD[j], 0.f);
      pC[j] = fc; pX[j] = fx; pD[j] = fd;
      lsC += fc; lsX += fx; lsD += fd;
    }
    *(float4*)(sm + OFF_F1E + 0 * CSTR + 60 + t0) = vC;   // stored UNNORMALIZED
    *(float4*)(sm + OFF_F1E + 1 * CSTR + 60 + t0) = vX;
    *(float4*)(sm + OFF_F1E + 2 * CSTR + 60 + t0) = vD;
  }
  float SC = lsC, SX = lsX, SD = lsD;
  blk_red_sum3(SC, SX, SD, red);                     // barriers publish f1
  const float iC = 1.f / (SC + 1e-10f);
  const float iX = 1.f / (SX + 1e-10f);
  const float iD = 1.f / (SD + 1e-10f);

  // --- f1 halos(60) + Kc + w_sub stage (1/S folded into weights) ---
  for (int i = tid; i < 360; i += TPB) {
    const int c = i / 120, j = i - c * 120;
    const int dst = (j < 60) ? j : (1000 + j);          // right: 1060..1119
    const int src = (j < 60) ? (120 - j) : (1118 - j);
    sm[OFF_F1E + c * CSTR + dst] = sm[OFF_F1E + c * CSTR + src];
  }
  for (int i = tid; i < 363; i += TPB) {
    const int cin = i / 121, k = i - cin * 121;
    const float iv = (cin == 0) ? iC : ((cin == 1) ? iX : iD);
    const float* Pp = P_g + cin * 121 + k;
    sm[OFF_KC + cin * 124 + k] =
        fmaf(Wv[0], Pp[0], fmaf(Wv[1], Pp[363], Wv[2] * Pp[726])) * iv;
  }
  for (int i = tid; i < 1080; i += TPB) {
    const int row = i / 24, k = i - row * 24;
    const int cin = row - (row / 3) * 3;
    const float iv = (cin == 0) ? iC : ((cin == 1) ? iX : iD);
    sm[OFF_WS2 + i] = (k < 21) ? wsub_g[row * 21 + k] * iv : 0.f;
  }
  __syncthreads();                                   // B6

  // ---------------- composed 3x121 conv (regs) + vectorized phantom f2 ------
  float res[4] = {0, 0, 0, 0};
  if (tid < 250) {
    #pragma unroll
    for (int cin = 0; cin < 3; ++cin) {
      const float* xr = sm + OFF_F1E + cin * CSTR + t0;
      const float* kc = sm + OFF_KC + cin * 124;
      float xw[8];
      *(float4*)xw = ld4(xr); *(float4*)(xw + 4) = ld4(xr + 4);
      for (int g = 0; g < 120; g += 4) {
        float4 kw = ld4(kc + g);                     // LDS broadcast b128
        const float wv[4] = {kw.x, kw.y, kw.z, kw.w};
        #pragma unroll
        for (int kk = 0; kk < 4; ++kk)
          #pragma unroll
          for (int j = 0; j < 4; ++j) res[j] = fmaf(wv[kk], xw[kk + j], res[j]);
        #pragma unroll
        for (int j = 0; j < 4; ++j) xw[j] = xw[j + 4];
        *(float4*)(xw + 4) = ld4(xr + g + 8);
      }
      const float w120 = kc[120];
      #pragma unroll
      for (int j = 0; j < 4; ++j) res[j] = fmaf(w120, xw[j], res[j]);
    }
  }
  // phantom f2: 390 tasks (left 195, right 195), 4 outputs each
  for (int task = tid; task < 390; task += TPB) {
    const int side = (task >= 195) ? 1 : 0;
    const int r = task - 195 * side;
    const int ch = r / 13;
    const int gl = r - 13 * ch;
    float acc[4] = {0, 0, 0, 0};
    const float* wrb = sm + OFF_WS2 + ch * 72;
    if (side == 0) {
      const int xb = 4 * gl;
      #pragma unroll
      for (int cin = 0; cin < 3; ++cin)
        f2v_accum<0>(sm + OFF_F1E + cin * CSTR + xb, wrb + cin * 24, acc);
    } else {
      const int xb = 1048 + 4 * gl;
      #pragma unroll
      for (int cin = 0; cin < 3; ++cin)
        f2v_accum<2>(sm + OFF_F1E + cin * CSTR + xb, wrb + cin * 24, acc);
    }
    const int dst = OFF_F2V + ch * 104 + side * 52 + 4 * gl;
    if (gl < 12) {
      float4 st = {acc[0], acc[1], acc[2], acc[3]};
      *(float4*)(sm + dst) = st;
    } else {
      sm[dst] = acc[0]; sm[dst + 1] = acc[1];
    }
  }
  __syncthreads();                                   // B7

  // ---- edge-correction partials: 500 (q,tcol) tasks (round-0 memory pattern,
  //      Wv hoisted out of the loop: 3 accumulators, one combine) ----
  for (int task = tid; task < 500; task += TPB) {
    const int q = task / 100;
    const int tcol = task - q * 100;
    const float* f0 = sm + OFF_F2V + (3 * q) * 104;
    float c0 = 0.f, c1 = 0.f, c2 = 0.f;
    if (tcol < 50) {
      const int t = tcol;
      for (int a = 0; a <= 49 - t; ++a) {
        const int up = t + a;
        const float* wb = wcb_g + q * 303 + a * 3;
        c0 = fmaf(wb[0], f0[up], c0);
        c1 = fmaf(wb[1], f0[104 + up], c1);
        c2 = fmaf(wb[2], f0[208 + up], c2);
      }
    } else {
      const int tp = tcol;                           // t = 900+tp
      for (int d = 0; d <= tp - 50; ++d) {
        const int up = tp - d + 2;                   // +2: right-side layout shift
        const int a = 100 - d;
        const float* wb = wcb_g + q * 303 + a * 3;
        c0 = fmaf(wb[0], f0[up], c0);
        c1 = fmaf(wb[1], f0[104 + up], c1);
        c2 = fmaf(wb[2], f0[208 + up], c2);
      }
    }
    sm[OFF_PART + task] = fmaf(Wv[0], c0, fmaf(Wv[1], c1, Wv[2] * c2));
  }
  __syncthreads();                                   // B8

  // ---------------- apply corrections + register-resident epilogue ----------
  if (tid < 250 && (t0 < 52 || t0 >= 948)) {
    #pragma unroll
    for (int j = 0; j < 4; ++j) {
      const int t = t0 + j;
      if (t < 50) {
        float c = 0.f;
        #pragma unroll
        for (int q = 0; q < 5; ++q) c += sm[OFF_PART + q * 100 + t];
        res[j] -= c;
      } else if (t >= 950) {
        const int tc = t - 900;
        float c = 0.f;
        #pragma unroll
        for (int q = 0; q < 5; ++q) c += sm[OFF_PART + q * 100 + tc];
        res[j] -= c;
      }
    }
  }
  float sp[4], mj[4];
  float lm = -INFINITY, lmm = -INFINITY;
  if (tid < 250) {
    const float4 mv = ld4(mask_g + (size_t)b * LW + t0);
    mj[0] = mv.x; mj[1] = mv.y; mj[2] = mv.z; mj[3] = mv.w;
    #pragma unroll
    for (int j = 0; j < 4; ++j) {
      const float z = res[j];
      sp[j] = fmaxf(z, 0.f) + log1pf(expf(-fabsf(z)));   // stable softplus
      lm = fmaxf(lm, sp[j]);
      lmm = fmaxf(lmm, sp[j] * mj[j]);
    }
  }
  // fused dual block-max: amax over sp, mmax over sp*mask (m2 = 1e4*mmax/amax)
  #pragma unroll
  for (int o = 32; o > 0; o >>= 1) {
    lm = fmaxf(lm, __shfl_xor(lm, o, 64));
    lmm = fmaxf(lmm, __shfl_xor(lmm, o, 64));
  }
  {
    const int w = tid >> 6;
    if ((tid & 63) == 0) { red[w] = lm; red[4 + w] = lmm; }
  }
  __syncthreads();
  const float amax = fmaxf(fmaxf(red[0], red[1]), fmaxf(red[2], red[3])) + 1e-10f;
  const float mmax = fmaxf(fmaxf(red[4], red[5]), fmaxf(red[6], red[7]));
  __syncthreads();
  const float ia = 1e4f / amax;
  const float m2 = mmax * ia;
  float ls = 0.f;
  float e4[4];
  if (tid < 250) {
    #pragma unroll
    for (int j = 0; j < 4; ++j) {
      const float v = (sp[j] * ia) * mj[j];
      e4[j] = expf(v - m2);
      ls += e4[j];
    }
  }
  const float S2 = blk_red_sum(ls, red);
  if (tid < 250) {
    const float invs = 1.f / S2;
    float4 st = { e4[0] * invs, e4[1] * invs, e4[2] * invs, e4[3] * invs };
    *(float4*)(out_g + (size_t)b * LW + t0) = st;
  }
}

extern "C" void kernel_launch(void* const* d_in, const int* in_sizes, int n_in,
                              void* d_out, int out_size, void* d_ws, size_t ws_size,
                              hipStream_t stream) {
  (void)n_in; (void)ws_size; (void)out_size;
  const float* wf   = (const float*)d_in[0];
  const float* mask = (const float*)d_in[1];
  const float* spe  = (const float*)d_in[2];
  const float* wca  = (const float*)d_in[3];
  const float* wx   = (const float*)d_in[4];
  const float* wdv  = (const float*)d_in[5];
  const float* wrl  = (const float*)d_in[6];
  const float* wsub = (const float*)d_in[7];
  const float* wcb  = (const float*)d_in[8];
  const float* wp   = (const float*)d_in[9];
  float* P = (float*)d_ws;                       // 1212 floats
  const int B = in_sizes[0] / LW;
  hipLaunchKernelGGL(prep_kernel, dim3(5), dim3(TPB), 0, stream, wsub, wcb, wca, spe, wrl, P);
  hipLaunchKernelGGL(spot_kernel, dim3(B), dim3(TPB), 0, stream,
                     wf, mask, spe, wca, wx, wdv, wrl, wsub, wcb, wp, P, (float*)d_out);
}

// Round 3
// 326.982 us; speedup vs baseline: 1.0300x; 1.0300x over previous
//
#include <hip/hip_runtime.h>
#include <math.h>

#define TPB 256
#define LW  1000
#define CSTR 1124   // f1e per-channel stride (1000 + 2*60 halo + 4 pad)

// ---- LDS layout (float offsets) ----
#define OFF_WFE   0        // 1120: wf reflect-ext, orig [-100,1020), core at +100
#define OFF_CUME  1120     // 1120: cumsum reflect-ext, core at +100
#define OFF_DSE   2240     // 1120: div_x_smd reflect-ext, core at +100
#define OFF_F1E   3360     // 3372 (+pad): features1_norm, core at +60, stride 1124
#define OFF_SCAND 3360     // alias: 512 floats = 256 doubles (wf fp64 scan)
#define OFF_C     3872     // alias: 1000 floats (d1 cumsum)
#define OFF_RED   6740     // 8 reduction scratch
#define SMEM_F    6748     // 26,992 B -> 6 blocks/CU
// phase-2 aliases of [0,3360) (staging dead after fused conv):
#define OFF_KC    0        // 372 composed kernel
#define OFF_WS2   376      // 1080 = 15*3 rows, stride 24 (21 used)
#define OFF_F2V   1456     // 1560 = 15*104: phantom f2; left at [0,50), right at [52,102)
#define OFF_PART  0        // 500 (alias KC/WS2 head; written after their last use)

__device__ __forceinline__ float4 ld4(const float* p) { return *(const float4*)p; }

__device__ __forceinline__ float blk_red_max(float v, float* red) {
  #pragma unroll
  for (int o = 32; o > 0; o >>= 1) v = fmaxf(v, __shfl_xor(v, o, 64));
  const int w = threadIdx.x >> 6;
  if ((threadIdx.x & 63) == 0) red[w] = v;
  __syncthreads();
  float r = fmaxf(fmaxf(red[0], red[1]), fmaxf(red[2], red[3]));
  __syncthreads();
  return r;
}

__device__ __forceinline__ float blk_red_sum(float v, float* red) {
  #pragma unroll
  for (int o = 32; o > 0; o >>= 1) v += __shfl_xor(v, o, 64);
  const int w = threadIdx.x >> 6;
  if ((threadIdx.x & 63) == 0) red[w] = v;
  __syncthreads();
  float r = red[0] + red[1] + red[2] + red[3];
  __syncthreads();
  return r;
}

__device__ __forceinline__ int refl(int j) {
  return j < 0 ? -j : (j >= LW ? 2 * LW - 2 - j : j);
}

// phantom-f2 inner: 21-tap conv, 4 outputs, sliding b128 window.
// OFF0 is the compile-time misalignment (0 for left side, 2 for right side).
template<int OFF0>
__device__ __forceinline__ void f2v_accum(const float* xr, const float* wr, float acc[4]) {
  float xw[12];
  *(float4*)xw       = ld4(xr);
  *(float4*)(xw + 4) = ld4(xr + 4);
  *(float4*)(xw + 8) = ld4(xr + 8);
  #pragma unroll
  for (int jb = 0; jb < 20; jb += 4) {
    float4 w4 = ld4(wr + jb);
    const float wv[4] = {w4.x, w4.y, w4.z, w4.w};
    #pragma unroll
    for (int kk = 0; kk < 4; ++kk)
      #pragma unroll
      for (int o = 0; o < 4; ++o)
        acc[o] = fmaf(wv[kk], xw[OFF0 + kk + o], acc[o]);
    #pragma unroll
    for (int j = 0; j < 8; ++j) xw[j] = xw[j + 4];
    *(float4*)(xw + 8) = ld4(xr + jb + 12);
  }
  const float w20 = wr[20];
  #pragma unroll
  for (int o = 0; o < 4; ++o) acc[o] = fmaf(w20, xw[OFF0 + o], acc[o]);
}

// P[m][cin][k] = sum_q conv(wcb[q,:,m], wsub[3q+m][cin])[k], k in [0,121)
// P[1090] = max(SPE); P[1091+k] = wca[k] - sum(wca)*wrl[k] (wrl zero-extended)
extern "C" __global__ void prep_kernel(const float* __restrict__ wsub_g,
                                       const float* __restrict__ wcb_g,
                                       const float* __restrict__ wca_g,
                                       const float* __restrict__ spe_g,
                                       const float* __restrict__ wrl_g,
                                       float* __restrict__ P) {
  __shared__ float sred[4];
  __shared__ float s_swca;
  const int task = blockIdx.x * blockDim.x + threadIdx.x;
  if (task < 1089) {
    const int m = task / 363;
    const int r = task - m * 363;
    const int cin = r / 121;
    const int k = r - cin * 121;
    float acc = 0.f;
    for (int q = 0; q < 5; ++q) {
      const int ch = 3 * q + m;
      const float* ws = wsub_g + (ch * 3 + cin) * 21;
      #pragma unroll
      for (int j = 0; j < 21; ++j) {
        const int a = k - j;
        if (a >= 0 && a <= 100) acc = fmaf(ws[j], wcb_g[q * 303 + a * 3 + m], acc);
      }
    }
    P[task] = acc;
  }
  if (blockIdx.x == 4) {   // SPE max + combined cum/roll kernel
    float mx = -INFINITY;
    for (int t = threadIdx.x; t < LW; t += TPB) mx = fmaxf(mx, spe_g[t]);
    #pragma unroll
    for (int o = 32; o > 0; o >>= 1) mx = fmaxf(mx, __shfl_xor(mx, o, 64));
    if ((threadIdx.x & 63) == 0) sred[threadIdx.x >> 6] = mx;
    if (threadIdx.x == 0) {
      float s = 0.f;
      for (int k = 0; k < 121; ++k) s += wca_g[k];
      s_swca = s;
    }
    __syncthreads();
    if (threadIdx.x == 0)
      P[1090] = fmaxf(fmaxf(sred[0], sred[1]), fmaxf(sred[2], sred[3]));
    if (threadIdx.x < 121) {
      const int k = threadIdx.x;
      float w = 0.f;
      if (k < 101) w = wrl_g[k];
      P[1091 + k] = wca_g[k] - s_swca * w;
    }
  }
}

extern "C" __global__ void __launch_bounds__(TPB, 6)
spot_kernel(const float* __restrict__ wf_g,  const float* __restrict__ mask_g,
            const float* __restrict__ spe_g, const float* __restrict__ wca_g,
            const float* __restrict__ wx_g,  const float* __restrict__ wdv_g,
            const float* __restrict__ wrl_g, const float* __restrict__ wsub_g,
            const float* __restrict__ wcb_g, const float* __restrict__ wp_g,
            const float* __restrict__ P_g,   float* __restrict__ out_g)
{
  __shared__ __align__(16) float sm[SMEM_F];
  const int tid = threadIdx.x;
  const int b = blockIdx.x;
  const float* wf = wf_g + (size_t)b * LW;
  float* red = sm + OFF_RED;
  const int t0 = 4 * tid;

  // ---------------- phase 0: staging, maxima, wf fp64 scan partials ----------
  for (int i = tid; i < 1120; i += TPB) sm[OFF_WFE + i] = wf[refl(i - 100)];
  double* scand = (double*)(sm + OFF_SCAND);
  double l0 = 0, l1 = 0, l2 = 0, l3 = 0;
  float hmx = -INFINITY;
  if (tid < 250) {
    float4 wv4 = ld4(wf + t0);
    hmx = fmaxf(fmaxf(wv4.x, wv4.y), fmaxf(wv4.z, wv4.w));
    l0 = (double)wv4.x;
    l1 = l0 + (double)wv4.y;
    l2 = l1 + (double)wv4.z;
    l3 = l2 + (double)wv4.w;
  }
  scand[tid] = l3;
  hmx = blk_red_max(hmx, red);   // barriers publish wfe/scand

  // per-sample 3-way mixing weights W
  const float smx = P_g[1090];
  const float h = hmx / smx;
  float a0 = -fmaxf(h - wp_g[0], 0.f);
  float a1 = -fmaxf(h - wp_g[1], 0.f);
  float a2 = -fmaxf(h - wp_g[2], 0.f);
  float am = fmaxf(a0, fmaxf(a1, a2));
  float e0 = expf(a0 - am), e1 = expf(a1 - am), e2 = expf(a2 - am);
  float es = e0 + e1 + e2;
  float Wv[3] = { e0 / es, e1 / es, e2 / es };

  // ---------------- wf cumsum: fp64 block scan ----------------
  if (tid < 64) {
    double s0 = scand[4 * tid], s1 = scand[4 * tid + 1];
    double s2 = scand[4 * tid + 2], s3 = scand[4 * tid + 3];
    double tot = s0 + s1 + s2 + s3;
    double inc = tot;
    #pragma unroll
    for (int o = 1; o < 64; o <<= 1) {
      double n = __shfl_up(inc, o, 64);
      if ((tid & 63) >= o) inc += n;
    }
    double ex = inc - tot;
    scand[4 * tid]     = ex;
    scand[4 * tid + 1] = ex + s0;
    scand[4 * tid + 2] = ex + s0 + s1;
    scand[4 * tid + 3] = ex + s0 + s1 + s2;
  }
  __syncthreads();                                   // B1
  if (tid < 250) {
    double base = scand[tid];
    float4 cv = { (float)(base + l0), (float)(base + l1),
                  (float)(base + l2), (float)(base + l3) };
    *(float4*)(sm + OFF_CUME + 100 + t0) = cv;
  }
  // d1 (9-tap derivative, zero-padded) in registers + fp32 scan partials
  const float dker[9] = {1.f/280.f, -4.f/105.f, 0.2f, -0.8f, 0.f, 0.8f, -0.2f, 4.f/105.f, -1.f/280.f};
  float dv0 = 0, dv1 = 0, dv2 = 0, dv3 = 0;
  if (tid >= 1 && tid <= 248) {          // safe interior: orig window [t0-4, t0+7]
    float xw[12];
    const float* xr = sm + OFF_WFE + t0 + 96;
    *(float4*)xw = ld4(xr); *(float4*)(xw+4) = ld4(xr+4); *(float4*)(xw+8) = ld4(xr+8);
    float d[4];
    #pragma unroll
    for (int j = 0; j < 4; ++j) {
      float a = 0.f;
      #pragma unroll
      for (int k = 0; k < 9; ++k) {
        if (k == 4) continue;
        a = fmaf(dker[k], xw[j + k], a);
      }
      d[j] = a;
    }
    dv0 = d[0]; dv1 = d[1]; dv2 = d[2]; dv3 = d[3];
  } else if (tid == 0 || tid == 249) {   // edges: zero-padded scalar path
    float d[4];
    #pragma unroll
    for (int j = 0; j < 4; ++j) {
      float a = 0.f;
      for (int k = 0; k < 9; ++k) {
        if (k == 4) continue;
        const int o = t0 + j - 4 + k;
        if (o >= 0 && o < LW) a = fmaf(dker[k], sm[OFF_WFE + 100 + o], a);
      }
      d[j] = a;
    }
    dv0 = d[0]; dv1 = d[1]; dv2 = d[2]; dv3 = d[3];
  }
  // fp32 scan of d1
  {
    const float s0 = dv0, s1 = s0 + dv1, s2 = s1 + dv2, s3 = s2 + dv3;
    float inc = s3;
    const int lane = tid & 63;
    #pragma unroll
    for (int o = 1; o < 64; o <<= 1) {
      float n = __shfl_up(inc, o, 64);
      if (lane >= o) inc += n;
    }
    float* redw = red + 4;
    if (lane == 63) redw[tid >> 6] = inc;
    __syncthreads();                                 // B2 (publishes CUME core too)
    float base = 0.f;
    for (int w = 0; w < (tid >> 6); ++w) base += redw[w];
    if (tid < 250) {
      const float ex = base + inc - s3;
      float4 cv = { ex + s0, ex + s1, ex + s2, ex + s3 };
      *(float4*)(sm + OFF_C + t0) = cv;
    }
  }
  __syncthreads();                                   // B3
  // dse core = (C[t+25]-C[t-26])/51 ; cume halos
  for (int t = tid; t < LW; t += TPB) {
    const float hi = sm[OFF_C + (t + 25 > 999 ? 999 : t + 25)];
    const float lo = (t >= 26) ? sm[OFF_C + t - 26] : 0.f;
    sm[OFF_DSE + 100 + t] = (hi - lo) * (1.f / 51.f);
  }
  for (int i = tid; i < 120; i += TPB) {
    if (i < 100) sm[OFF_CUME + i] = sm[OFF_CUME + 200 - i];
    else         sm[OFF_CUME + 1000 + i] = sm[OFF_CUME + 2198 - (1000 + i)];
  }
  __syncthreads();                                   // B4
  for (int i = tid; i < 120; i += TPB) {
    if (i < 100) sm[OFF_DSE + i] = sm[OFF_DSE + 200 - i];
    else         sm[OFF_DSE + 1000 + i] = sm[OFF_DSE + 2198 - (1000 + i)];
  }
  __syncthreads();                                   // B5

  // ------- fused reflect convs -> features1 (3 kernels: kCB, wx, wdv) -------
  float lsC = 0.f, lsX = 0.f, lsD = 0.f;
  if (tid < 250) {
    const float* ce = sm + OFF_CUME + t0;
    const float* we = sm + OFF_WFE + t0;
    const float* de = sm + OFF_DSE + t0;
    const float* kcb = P_g + 1091;                   // wca - sum(wca)*wrl, precomposed
    float cw_[8], ww_[8], dw_[8];
    *(float4*)cw_ = ld4(ce); *(float4*)(cw_ + 4) = ld4(ce + 4);
    *(float4*)ww_ = ld4(we); *(float4*)(ww_ + 4) = ld4(we + 4);
    *(float4*)dw_ = ld4(de); *(float4*)(dw_ + 4) = ld4(de + 4);
    float aC[4] = {0,0,0,0}, aX[4] = {0,0,0,0}, aD[4] = {0,0,0,0};
    for (int g = 0; g < 116; g += 4) {               // taps 0..115
      #pragma unroll
      for (int kk = 0; kk < 4; ++kk) {
        const int k = g + kk;
        const float wc = kcb[k], wxk = wx_g[k], wdk = wdv_g[k];
        #pragma unroll
        for (int j = 0; j < 4; ++j) {
          aC[j] = fmaf(wc,  cw_[kk + j], aC[j]);
          aX[j] = fmaf(wxk, ww_[kk + j], aX[j]);
          aD[j] = fmaf(wdk, dw_[kk + j], aD[j]);
        }
      }
      #pragma unroll
      for (int j = 0; j < 4; ++j) { cw_[j] = cw_[j+4]; ww_[j] = ww_[j+4]; dw_[j] = dw_[j+4]; }
      *(float4*)(cw_ + 4) = ld4(ce + g + 8);
      *(float4*)(ww_ + 4) = ld4(we + g + 8);
      *(float4*)(dw_ + 4) = ld4(de + g + 8);
    }
    #pragma unroll
    for (int kk = 0; kk < 5; ++kk) {                 // taps 116..120 from window
      const int k = 116 + kk;
      const float wc = kcb[k], wxk = wx_g[k], wdk = wdv_g[k];
      #pragma unroll
      for (int j = 0; j < 4; ++j) {
        aC[j] = fmaf(wc,  cw_[kk + j], aC[j]);
        aX[j] = fmaf(wxk, ww_[kk + j], aX[j]);
        aD[j] = fmaf(wdk, dw_[kk + j], aD[j]);
      }
    }
    float4 vC, vX, vD;
    float* pC = (float*)&vC; float* pX = (float*)&vX; float* pD = (float*)&vD;
    #pragma unroll
    for (int j = 0; j < 4; ++j) {
      float fc = fmaxf(aC[j], 0.f);
      float fx = fmaxf(aX[j], 0.f);
      float fd = fmaxf(aD[j], 0.f);
      pC[j] = fc; pX[j] = fx; pD[j] = fd;
      lsC += fc; lsX += fx; lsD += fd;
    }
    *(float4*)(sm + OFF_F1E + 0 * CSTR + 60 + t0) = vC;
    *(float4*)(sm + OFF_F1E + 1 * CSTR + 60 + t0) = vX;
    *(float4*)(sm + OFF_F1E + 2 * CSTR + 60 + t0) = vD;
  }
  const float SC = blk_red_sum(lsC, red) + 1e-10f;   // barriers publish f1
  const float SX = blk_red_sum(lsX, red) + 1e-10f;
  const float SD = blk_red_sum(lsD, red) + 1e-10f;
  {
    const float iC = 1.f / SC, iX = 1.f / SX, iD = 1.f / SD;
    for (int t = tid; t < LW; t += TPB) {
      sm[OFF_F1E + 0 * CSTR + 60 + t] *= iC;
      sm[OFF_F1E + 1 * CSTR + 60 + t] *= iX;
      sm[OFF_F1E + 2 * CSTR + 60 + t] *= iD;
    }
  }
  __syncthreads();                                   // B6

  // ---------------- f1 halos(60) + Kc + w_sub stage (staging dead) ----------
  for (int i = tid; i < 360; i += TPB) {
    const int c = i / 120, j = i - c * 120;
    const int dst = (j < 60) ? j : (1000 + j);          // right: 1060..1119
    const int src = (j < 60) ? (120 - j) : (1118 - j);
    sm[OFF_F1E + c * CSTR + dst] = sm[OFF_F1E + c * CSTR + src];
  }
  for (int i = tid; i < 363; i += TPB) {
    const int cin = i / 121, k = i - cin * 121;
    const float* Pp = P_g + cin * 121 + k;
    sm[OFF_KC + cin * 124 + k] =
        fmaf(Wv[0], Pp[0], fmaf(Wv[1], Pp[363], Wv[2] * Pp[726]));
  }
  for (int i = tid; i < 1080; i += TPB) {
    const int row = i / 24, k = i - row * 24;
    sm[OFF_WS2 + i] = (k < 21) ? wsub_g[row * 21 + k] : 0.f;
  }
  __syncthreads();                                   // B7

  // ---------------- composed 3x121 conv (regs) + vectorized phantom f2 ------
  float res[4] = {0, 0, 0, 0};
  if (tid < 250) {
    #pragma unroll
    for (int cin = 0; cin < 3; ++cin) {
      const float* xr = sm + OFF_F1E + cin * CSTR + t0;
      const float* kc = sm + OFF_KC + cin * 124;
      float xw[8];
      *(float4*)xw = ld4(xr); *(float4*)(xw + 4) = ld4(xr + 4);
      for (int g = 0; g < 120; g += 4) {
        float4 kw = ld4(kc + g);                     // LDS broadcast b128
        const float wv[4] = {kw.x, kw.y, kw.z, kw.w};
        #pragma unroll
        for (int kk = 0; kk < 4; ++kk)
          #pragma unroll
          for (int j = 0; j < 4; ++j) res[j] = fmaf(wv[kk], xw[kk + j], res[j]);
        #pragma unroll
        for (int j = 0; j < 4; ++j) xw[j] = xw[j + 4];
        *(float4*)(xw + 4) = ld4(xr + g + 8);
      }
      const float w120 = kc[120];
      #pragma unroll
      for (int j = 0; j < 4; ++j) res[j] = fmaf(w120, xw[j], res[j]);
    }
  }
  // phantom f2: 390 tasks (left 195, right 195), 4 outputs each
  for (int task = tid; task < 390; task += TPB) {
    const int side = (task >= 195) ? 1 : 0;
    const int r = task - 195 * side;
    const int ch = r / 13;
    const int gl = r - 13 * ch;
    float acc[4] = {0, 0, 0, 0};
    const float* wrb = sm + OFF_WS2 + ch * 72;
    if (side == 0) {
      const int xb = 4 * gl;
      #pragma unroll
      for (int cin = 0; cin < 3; ++cin)
        f2v_accum<0>(sm + OFF_F1E + cin * CSTR + xb, wrb + cin * 24, acc);
    } else {
      const int xb = 1048 + 4 * gl;
      #pragma unroll
      for (int cin = 0; cin < 3; ++cin)
        f2v_accum<2>(sm + OFF_F1E + cin * CSTR + xb, wrb + cin * 24, acc);
    }
    const int dst = OFF_F2V + ch * 104 + side * 52 + 4 * gl;
    if (gl < 12) {
      float4 st = {acc[0], acc[1], acc[2], acc[3]};
      *(float4*)(sm + dst) = st;
    } else {
      sm[dst] = acc[0]; sm[dst + 1] = acc[1];
    }
  }
  __syncthreads();                                   // B8

  // ---------------- edge-correction partials: 500 (q,tcol) tasks ------------
  for (int task = tid; task < 500; task += TPB) {
    const int q = task / 100;
    const int tcol = task - q * 100;
    const float* f0 = sm + OFF_F2V + (3 * q) * 104;
    float acc = 0.f;
    if (tcol < 50) {
      const int t = tcol;
      for (int a = 0; a <= 49 - t; ++a) {
        const int up = t + a;
        const float* wb = wcb_g + q * 303 + a * 3;
        acc = fmaf(Wv[0] * wb[0], f0[up], acc);
        acc = fmaf(Wv[1] * wb[1], f0[104 + up], acc);
        acc = fmaf(Wv[2] * wb[2], f0[208 + up], acc);
      }
    } else {
      const int tp = tcol;                           // t = 900+tp
      for (int d = 0; d <= tp - 50; ++d) {
        const int up = tp - d + 2;                   // +2: right-side layout shift
        const int a = 100 - d;
        const float* wb = wcb_g + q * 303 + a * 3;
        acc = fmaf(Wv[0] * wb[0], f0[up], acc);
        acc = fmaf(Wv[1] * wb[1], f0[104 + up], acc);
        acc = fmaf(Wv[2] * wb[2], f0[208 + up], acc);
      }
    }
    sm[OFF_PART + task] = acc;                       // PART[q*100+tcol]
  }
  __syncthreads();                                   // B9

  // ---------------- apply corrections + register-resident epilogue ----------
  if (tid < 250 && (t0 < 52 || t0 >= 948)) {
    #pragma unroll
    for (int j = 0; j < 4; ++j) {
      const int t = t0 + j;
      if (t < 50) {
        float c = 0.f;
        #pragma unroll
        for (int q = 0; q < 5; ++q) c += sm[OFF_PART + q * 100 + t];
        res[j] -= c;
      } else if (t >= 950) {
        const int tc = t - 900;
        float c = 0.f;
        #pragma unroll
        for (int q = 0; q < 5; ++q) c += sm[OFF_PART + q * 100 + tc];
        res[j] -= c;
      }
    }
  }
  float sp[4];
  float lm = -INFINITY;
  if (tid < 250) {
    #pragma unroll
    for (int j = 0; j < 4; ++j) {
      const float z = res[j];
      sp[j] = fmaxf(z, 0.f) + log1pf(expf(-fabsf(z)));   // stable softplus
      lm = fmaxf(lm, sp[j]);
    }
  }
  const float amax = blk_red_max(lm, red) + 1e-10f;
  float v4[4];
  float lm2 = -INFINITY;
  if (tid < 250) {
    const float4 mv = ld4(mask_g + (size_t)b * LW + t0);
    const float* mj = (const float*)&mv;
    const float ia = 1e4f / amax;
    #pragma unroll
    for (int j = 0; j < 4; ++j) {
      v4[j] = (sp[j] * ia) * mj[j];
      lm2 = fmaxf(lm2, v4[j]);
    }
  }
  const float m2 = blk_red_max(lm2, red);
  float ls = 0.f;
  float e4[4];
  if (tid < 250) {
    #pragma unroll
    for (int j = 0; j < 4; ++j) {
      e4[j] = expf(v4[j] - m2);
      ls += e4[j];
    }
  }
  const float S2 = blk_red_sum(ls, red);
  if (tid < 250) {
    const float invs = 1.f / S2;
    float4 st = { e4[0] * invs, e4[1] * invs, e4[2] * invs, e4[3] * invs };
    *(float4*)(out_g + (size_t)b * LW + t0) = st;
  }
}

extern "C" void kernel_launch(void* const* d_in, const int* in_sizes, int n_in,
                              void* d_out, int out_size, void* d_ws, size_t ws_size,
                              hipStream_t stream) {
  (void)n_in; (void)ws_size; (void)out_size;
  const float* wf   = (const float*)d_in[0];
  const float* mask = (const float*)d_in[1];
  const float* spe  = (const float*)d_in[2];
  const float* wca  = (const float*)d_in[3];
  const float* wx   = (const float*)d_in[4];
  const float* wdv  = (const float*)d_in[5];
  const float* wrl  = (const float*)d_in[6];
  const float* wsub = (const float*)d_in[7];
  const float* wcb  = (const float*)d_in[8];
  const float* wp   = (const float*)d_in[9];
  float* P = (float*)d_ws;                       // 1212 floats
  const int B = in_sizes[0] / LW;
  hipLaunchKernelGGL(prep_kernel, dim3(5), dim3(TPB), 0, stream, wsub, wcb, wca, spe, wrl, P);
  hipLaunchKernelGGL(spot_kernel, dim3(B), dim3(TPB), 0, stream,
                     wf, mask, spe, wca, wx, wdv, wrl, wsub, wcb, wp, P, (float*)d_out);
}

// Round 4
// 290.853 us; speedup vs baseline: 1.1579x; 1.1242x over previous
//
#include <hip/hip_runtime.h>
#include <math.h>

#define TPB 256
#define LW  1000
#define CSTR 1124   // f1e per-channel stride (1000 + 2*60 halo + 4 pad)

// ---- LDS layout (float offsets) ----
#define OFF_WFE   0        // 1120: wf reflect-ext, orig [-100,1020), core at +100
#define OFF_CUME  1120     // 1120: cumsum reflect-ext, core at +100
#define OFF_DSE   2240     // 1120: div_x_smd reflect-ext, core at +100
#define OFF_F1E   3360     // 3372 (+pad): features1_norm, core at +60, stride 1124
#define OFF_SCAND 3360     // alias: 512 floats = 256 doubles (wf fp64 scan)
#define OFF_C     3872     // alias: 1000 floats (d1 cumsum)
#define OFF_RED   6740     // 8 reduction scratch
#define SMEM_F    6748     // 26,992 B -> 6 blocks/CU
// phase-2 aliases of [0,3360) (staging dead after fused conv):
#define OFF_KC    0        // 372 composed kernel
#define OFF_WS2   376      // 1080 = 15*3 rows, stride 24 (21 used)
#define OFF_F2V   1456     // 1560 = 15*104: phantom f2; left at [0,50), right at [52,102)
#define OFF_PART  0        // 500 (alias KC/WS2 head; written after their last use)

__device__ __forceinline__ float4 ld4(const float* p) { return *(const float4*)p; }

__device__ __forceinline__ float blk_red_max(float v, float* red) {
  #pragma unroll
  for (int o = 32; o > 0; o >>= 1) v = fmaxf(v, __shfl_xor(v, o, 64));
  const int w = threadIdx.x >> 6;
  if ((threadIdx.x & 63) == 0) red[w] = v;
  __syncthreads();
  float r = fmaxf(fmaxf(red[0], red[1]), fmaxf(red[2], red[3]));
  __syncthreads();
  return r;
}

__device__ __forceinline__ float blk_red_sum(float v, float* red) {
  #pragma unroll
  for (int o = 32; o > 0; o >>= 1) v += __shfl_xor(v, o, 64);
  const int w = threadIdx.x >> 6;
  if ((threadIdx.x & 63) == 0) red[w] = v;
  __syncthreads();
  float r = red[0] + red[1] + red[2] + red[3];
  __syncthreads();
  return r;
}

__device__ __forceinline__ int refl(int j) {
  return j < 0 ? -j : (j >= LW ? 2 * LW - 2 - j : j);
}

// phantom-f2 inner: 21-tap conv, 4 outputs, sliding b128 window.
// OFF0 is the compile-time misalignment (0 for left side, 2 for right side).
template<int OFF0>
__device__ __forceinline__ void f2v_accum(const float* xr, const float* wr, float acc[4]) {
  float xw[12];
  *(float4*)xw       = ld4(xr);
  *(float4*)(xw + 4) = ld4(xr + 4);
  *(float4*)(xw + 8) = ld4(xr + 8);
  #pragma unroll
  for (int jb = 0; jb < 20; jb += 4) {
    float4 w4 = ld4(wr + jb);
    const float wv[4] = {w4.x, w4.y, w4.z, w4.w};
    #pragma unroll
    for (int kk = 0; kk < 4; ++kk)
      #pragma unroll
      for (int o = 0; o < 4; ++o)
        acc[o] = fmaf(wv[kk], xw[OFF0 + kk + o], acc[o]);
    #pragma unroll
    for (int j = 0; j < 8; ++j) xw[j] = xw[j + 4];
    *(float4*)(xw + 8) = ld4(xr + jb + 12);
  }
  const float w20 = wr[20];
  #pragma unroll
  for (int o = 0; o < 4; ++o) acc[o] = fmaf(w20, xw[OFF0 + o], acc[o]);
}

// P[m][cin][k] = sum_q conv(wcb[q,:,m], wsub[3q+m][cin])[k], k in [0,121)
// P[1089] = sum(wca); P[1090] = max(SPE)
extern "C" __global__ void prep_kernel(const float* __restrict__ wsub_g,
                                       const float* __restrict__ wcb_g,
                                       const float* __restrict__ wca_g,
                                       const float* __restrict__ spe_g,
                                       float* __restrict__ P) {
  __shared__ float sred[4];
  const int task = blockIdx.x * blockDim.x + threadIdx.x;
  if (task < 1089) {
    const int m = task / 363;
    const int r = task - m * 363;
    const int cin = r / 121;
    const int k = r - cin * 121;
    float acc = 0.f;
    for (int q = 0; q < 5; ++q) {
      const int ch = 3 * q + m;
      const float* ws = wsub_g + (ch * 3 + cin) * 21;
      #pragma unroll
      for (int j = 0; j < 21; ++j) {
        const int a = k - j;
        if (a >= 0 && a <= 100) acc = fmaf(ws[j], wcb_g[q * 303 + a * 3 + m], acc);
      }
    }
    P[task] = acc;
  } else if (task == 1089) {
    float s = 0.f;
    for (int k = 0; k < 121; ++k) s += wca_g[k];
    P[1089] = s;
  }
  if (blockIdx.x == 4) {   // SPE max
    float mx = -INFINITY;
    for (int t = threadIdx.x; t < LW; t += TPB) mx = fmaxf(mx, spe_g[t]);
    #pragma unroll
    for (int o = 32; o > 0; o >>= 1) mx = fmaxf(mx, __shfl_xor(mx, o, 64));
    if ((threadIdx.x & 63) == 0) sred[threadIdx.x >> 6] = mx;
    __syncthreads();
    if (threadIdx.x == 0)
      P[1090] = fmaxf(fmaxf(sred[0], sred[1]), fmaxf(sred[2], sred[3]));
  }
}

extern "C" __global__ void __launch_bounds__(TPB, 4)
spot_kernel(const float* __restrict__ wf_g,  const float* __restrict__ mask_g,
            const float* __restrict__ spe_g, const float* __restrict__ wca_g,
            const float* __restrict__ wx_g,  const float* __restrict__ wdv_g,
            const float* __restrict__ wrl_g, const float* __restrict__ wsub_g,
            const float* __restrict__ wcb_g, const float* __restrict__ wp_g,
            const float* __restrict__ P_g,   float* __restrict__ out_g)
{
  __shared__ __align__(16) float sm[SMEM_F];
  const int tid = threadIdx.x;
  const int b = blockIdx.x;
  const float* wf = wf_g + (size_t)b * LW;
  float* red = sm + OFF_RED;
  const int t0 = 4 * tid;

  // ---------------- phase 0: staging, maxima, wf fp64 scan partials ----------
  for (int i = tid; i < 1120; i += TPB) sm[OFF_WFE + i] = wf[refl(i - 100)];
  double* scand = (double*)(sm + OFF_SCAND);
  double l0 = 0, l1 = 0, l2 = 0, l3 = 0;
  float hmx = -INFINITY;
  if (tid < 250) {
    float4 wv4 = ld4(wf + t0);
    hmx = fmaxf(fmaxf(wv4.x, wv4.y), fmaxf(wv4.z, wv4.w));
    l0 = (double)wv4.x;
    l1 = l0 + (double)wv4.y;
    l2 = l1 + (double)wv4.z;
    l3 = l2 + (double)wv4.w;
  }
  scand[tid] = l3;
  hmx = blk_red_max(hmx, red);   // barriers publish wfe/scand

  // per-sample 3-way mixing weights W
  const float smx = P_g[1090];
  const float swca = P_g[1089];
  const float h = hmx / smx;
  float a0 = -fmaxf(h - wp_g[0], 0.f);
  float a1 = -fmaxf(h - wp_g[1], 0.f);
  float a2 = -fmaxf(h - wp_g[2], 0.f);
  float am = fmaxf(a0, fmaxf(a1, a2));
  float e0 = expf(a0 - am), e1 = expf(a1 - am), e2 = expf(a2 - am);
  float es = e0 + e1 + e2;
  float Wv[3] = { e0 / es, e1 / es, e2 / es };

  // ---------------- wf cumsum: fp64 block scan ----------------
  if (tid < 64) {
    double s0 = scand[4 * tid], s1 = scand[4 * tid + 1];
    double s2 = scand[4 * tid + 2], s3 = scand[4 * tid + 3];
    double tot = s0 + s1 + s2 + s3;
    double inc = tot;
    #pragma unroll
    for (int o = 1; o < 64; o <<= 1) {
      double n = __shfl_up(inc, o, 64);
      if ((tid & 63) >= o) inc += n;
    }
    double ex = inc - tot;
    scand[4 * tid]     = ex;
    scand[4 * tid + 1] = ex + s0;
    scand[4 * tid + 2] = ex + s0 + s1;
    scand[4 * tid + 3] = ex + s0 + s1 + s2;
  }
  __syncthreads();                                   // B1
  if (tid < 250) {
    double base = scand[tid];
    float4 cv = { (float)(base + l0), (float)(base + l1),
                  (float)(base + l2), (float)(base + l3) };
    *(float4*)(sm + OFF_CUME + 100 + t0) = cv;
  }
  // d1 (9-tap derivative, zero-padded) in registers + fp32 scan partials
  const float dker[9] = {1.f/280.f, -4.f/105.f, 0.2f, -0.8f, 0.f, 0.8f, -0.2f, 4.f/105.f, -1.f/280.f};
  float dv0 = 0, dv1 = 0, dv2 = 0, dv3 = 0;
  if (tid >= 1 && tid <= 248) {          // safe interior: orig window [t0-4, t0+7]
    float xw[12];
    const float* xr = sm + OFF_WFE + t0 + 96;
    *(float4*)xw = ld4(xr); *(float4*)(xw+4) = ld4(xr+4); *(float4*)(xw+8) = ld4(xr+8);
    float d[4];
    #pragma unroll
    for (int j = 0; j < 4; ++j) {
      float a = 0.f;
      #pragma unroll
      for (int k = 0; k < 9; ++k) {
        if (k == 4) continue;
        a = fmaf(dker[k], xw[j + k], a);
      }
      d[j] = a;
    }
    dv0 = d[0]; dv1 = d[1]; dv2 = d[2]; dv3 = d[3];
  } else if (tid == 0 || tid == 249) {   // edges: zero-padded scalar path
    float d[4];
    #pragma unroll
    for (int j = 0; j < 4; ++j) {
      float a = 0.f;
      for (int k = 0; k < 9; ++k) {
        if (k == 4) continue;
        const int o = t0 + j - 4 + k;
        if (o >= 0 && o < LW) a = fmaf(dker[k], sm[OFF_WFE + 100 + o], a);
      }
      d[j] = a;
    }
    dv0 = d[0]; dv1 = d[1]; dv2 = d[2]; dv3 = d[3];
  }
  // fp32 scan of d1
  {
    const float s0 = dv0, s1 = s0 + dv1, s2 = s1 + dv2, s3 = s2 + dv3;
    float inc = s3;
    const int lane = tid & 63;
    #pragma unroll
    for (int o = 1; o < 64; o <<= 1) {
      float n = __shfl_up(inc, o, 64);
      if (lane >= o) inc += n;
    }
    float* redw = red + 4;
    if (lane == 63) redw[tid >> 6] = inc;
    __syncthreads();                                 // B2 (publishes CUME core too)
    float base = 0.f;
    for (int w = 0; w < (tid >> 6); ++w) base += redw[w];
    if (tid < 250) {
      const float ex = base + inc - s3;
      float4 cv = { ex + s0, ex + s1, ex + s2, ex + s3 };
      *(float4*)(sm + OFF_C + t0) = cv;
    }
  }
  __syncthreads();                                   // B3
  // dse core = (C[t+25]-C[t-26])/51 ; cume halos
  for (int t = tid; t < LW; t += TPB) {
    const float hi = sm[OFF_C + (t + 25 > 999 ? 999 : t + 25)];
    const float lo = (t >= 26) ? sm[OFF_C + t - 26] : 0.f;
    sm[OFF_DSE + 100 + t] = (hi - lo) * (1.f / 51.f);
  }
  for (int i = tid; i < 120; i += TPB) {
    if (i < 100) sm[OFF_CUME + i] = sm[OFF_CUME + 200 - i];
    else         sm[OFF_CUME + 1000 + i] = sm[OFF_CUME + 2198 - (1000 + i)];
  }
  __syncthreads();                                   // B4
  for (int i = tid; i < 120; i += TPB) {
    if (i < 100) sm[OFF_DSE + i] = sm[OFF_DSE + 200 - i];
    else         sm[OFF_DSE + 1000 + i] = sm[OFF_DSE + 2198 - (1000 + i)];
  }
  __syncthreads();                                   // B5

  // ---------------- fused 121/101-tap reflect convs -> features1 ------------
  float lsC = 0.f, lsX = 0.f, lsD = 0.f;
  if (tid < 250) {
    const float* ce = sm + OFF_CUME + t0;
    const float* we = sm + OFF_WFE + t0;
    const float* de = sm + OFF_DSE + t0;
    float cw_[8], ww_[8], dw_[8];
    *(float4*)cw_ = ld4(ce); *(float4*)(cw_ + 4) = ld4(ce + 4);
    *(float4*)ww_ = ld4(we); *(float4*)(ww_ + 4) = ld4(we + 4);
    *(float4*)dw_ = ld4(de); *(float4*)(dw_ + 4) = ld4(de + 4);
    float aC[4] = {0,0,0,0}, aB[4] = {0,0,0,0}, aX[4] = {0,0,0,0}, aD[4] = {0,0,0,0};
    for (int g = 0; g < 100; g += 4) {               // taps 0..99, all four convs
      #pragma unroll
      for (int kk = 0; kk < 4; ++kk) {
        const int k = g + kk;
        const float wa = wca_g[k], wxk = wx_g[k], wdk = wdv_g[k], wr = wrl_g[k];
        #pragma unroll
        for (int j = 0; j < 4; ++j) {
          aC[j] = fmaf(wa,  cw_[kk + j], aC[j]);
          aB[j] = fmaf(wr,  cw_[kk + j], aB[j]);
          aX[j] = fmaf(wxk, ww_[kk + j], aX[j]);
          aD[j] = fmaf(wdk, dw_[kk + j], aD[j]);
        }
      }
      #pragma unroll
      for (int j = 0; j < 4; ++j) { cw_[j] = cw_[j+4]; ww_[j] = ww_[j+4]; dw_[j] = dw_[j+4]; }
      *(float4*)(cw_ + 4) = ld4(ce + g + 8);
      *(float4*)(ww_ + 4) = ld4(we + g + 8);
      *(float4*)(dw_ + 4) = ld4(de + g + 8);
    }
    { // aB tap k=100 (window base = t0+100)
      const float wr100 = wrl_g[100];
      #pragma unroll
      for (int j = 0; j < 4; ++j) aB[j] = fmaf(wr100, cw_[j], aB[j]);
    }
    for (int g = 100; g < 116; g += 4) {             // taps 100..115, three convs
      #pragma unroll
      for (int kk = 0; kk < 4; ++kk) {
        const int k = g + kk;
        const float wa = wca_g[k], wxk = wx_g[k], wdk = wdv_g[k];
        #pragma unroll
        for (int j = 0; j < 4; ++j) {
          aC[j] = fmaf(wa,  cw_[kk + j], aC[j]);
          aX[j] = fmaf(wxk, ww_[kk + j], aX[j]);
          aD[j] = fmaf(wdk, dw_[kk + j], aD[j]);
        }
      }
      #pragma unroll
      for (int j = 0; j < 4; ++j) { cw_[j] = cw_[j+4]; ww_[j] = ww_[j+4]; dw_[j] = dw_[j+4]; }
      *(float4*)(cw_ + 4) = ld4(ce + g + 8);
      *(float4*)(ww_ + 4) = ld4(we + g + 8);
      *(float4*)(dw_ + 4) = ld4(de + g + 8);
    }
    #pragma unroll
    for (int kk = 0; kk < 5; ++kk) {                 // taps 116..120 from window
      const int k = 116 + kk;
      const float wa = wca_g[k], wxk = wx_g[k], wdk = wdv_g[k];
      #pragma unroll
      for (int j = 0; j < 4; ++j) {
        aC[j] = fmaf(wa,  cw_[kk + j], aC[j]);
        aX[j] = fmaf(wxk, ww_[kk + j], aX[j]);
        aD[j] = fmaf(wdk, dw_[kk + j], aD[j]);
      }
    }
    float4 vC, vX, vD;
    float* pC = (float*)&vC; float* pX = (float*)&vX; float* pD = (float*)&vD;
    #pragma unroll
    for (int j = 0; j < 4; ++j) {
      float fc = fmaxf(fmaf(-aB[j], swca, aC[j]), 0.f);
      float fx = fmaxf(aX[j], 0.f);
      float fd = fmaxf(aD[j], 0.f);
      pC[j] = fc; pX[j] = fx; pD[j] = fd;
      lsC += fc; lsX += fx; lsD += fd;
    }
    *(float4*)(sm + OFF_F1E + 0 * CSTR + 60 + t0) = vC;
    *(float4*)(sm + OFF_F1E + 1 * CSTR + 60 + t0) = vX;
    *(float4*)(sm + OFF_F1E + 2 * CSTR + 60 + t0) = vD;
  }
  const float SC = blk_red_sum(lsC, red) + 1e-10f;   // barriers publish f1
  const float SX = blk_red_sum(lsX, red) + 1e-10f;
  const float SD = blk_red_sum(lsD, red) + 1e-10f;
  {
    const float iC = 1.f / SC, iX = 1.f / SX, iD = 1.f / SD;
    for (int t = tid; t < LW; t += TPB) {
      sm[OFF_F1E + 0 * CSTR + 60 + t] *= iC;
      sm[OFF_F1E + 1 * CSTR + 60 + t] *= iX;
      sm[OFF_F1E + 2 * CSTR + 60 + t] *= iD;
    }
  }
  __syncthreads();                                   // B6

  // ---------------- f1 halos(60) + Kc + w_sub stage (staging dead) ----------
  for (int i = tid; i < 360; i += TPB) {
    const int c = i / 120, j = i - c * 120;
    const int dst = (j < 60) ? j : (1000 + j);          // right: 1060..1119
    const int src = (j < 60) ? (120 - j) : (1118 - j);
    sm[OFF_F1E + c * CSTR + dst] = sm[OFF_F1E + c * CSTR + src];
  }
  for (int i = tid; i < 363; i += TPB) {
    const int cin = i / 121, k = i - cin * 121;
    const float* Pp = P_g + cin * 121 + k;
    sm[OFF_KC + cin * 124 + k] =
        fmaf(Wv[0], Pp[0], fmaf(Wv[1], Pp[363], Wv[2] * Pp[726]));
  }
  for (int i = tid; i < 1080; i += TPB) {
    const int row = i / 24, k = i - row * 24;
    sm[OFF_WS2 + i] = (k < 21) ? wsub_g[row * 21 + k] : 0.f;
  }
  __syncthreads();                                   // B7

  // ---------------- composed 3x121 conv (regs) + vectorized phantom f2 ------
  float res[4] = {0, 0, 0, 0};
  if (tid < 250) {
    #pragma unroll
    for (int cin = 0; cin < 3; ++cin) {
      const float* xr = sm + OFF_F1E + cin * CSTR + t0;
      const float* kc = sm + OFF_KC + cin * 124;
      float xw[8];
      *(float4*)xw = ld4(xr); *(float4*)(xw + 4) = ld4(xr + 4);
      for (int g = 0; g < 120; g += 4) {
        float4 kw = ld4(kc + g);                     // LDS broadcast b128
        const float wv[4] = {kw.x, kw.y, kw.z, kw.w};
        #pragma unroll
        for (int kk = 0; kk < 4; ++kk)
          #pragma unroll
          for (int j = 0; j < 4; ++j) res[j] = fmaf(wv[kk], xw[kk + j], res[j]);
        #pragma unroll
        for (int j = 0; j < 4; ++j) xw[j] = xw[j + 4];
        *(float4*)(xw + 4) = ld4(xr + g + 8);
      }
      const float w120 = kc[120];
      #pragma unroll
      for (int j = 0; j < 4; ++j) res[j] = fmaf(w120, xw[j], res[j]);
    }
  }
  // phantom f2: 390 tasks (left 195, right 195), 4 outputs each
  for (int task = tid; task < 390; task += TPB) {
    const int side = (task >= 195) ? 1 : 0;
    const int r = task - 195 * side;
    const int ch = r / 13;
    const int gl = r - 13 * ch;
    float acc[4] = {0, 0, 0, 0};
    const float* wrb = sm + OFF_WS2 + ch * 72;
    if (side == 0) {
      const int xb = 4 * gl;
      #pragma unroll
      for (int cin = 0; cin < 3; ++cin)
        f2v_accum<0>(sm + OFF_F1E + cin * CSTR + xb, wrb + cin * 24, acc);
    } else {
      const int xb = 1048 + 4 * gl;
      #pragma unroll
      for (int cin = 0; cin < 3; ++cin)
        f2v_accum<2>(sm + OFF_F1E + cin * CSTR + xb, wrb + cin * 24, acc);
    }
    const int dst = OFF_F2V + ch * 104 + side * 52 + 4 * gl;
    if (gl < 12) {
      float4 st = {acc[0], acc[1], acc[2], acc[3]};
      *(float4*)(sm + dst) = st;
    } else {
      sm[dst] = acc[0]; sm[dst + 1] = acc[1];
    }
  }
  __syncthreads();                                   // B8

  // ---------------- edge-correction partials: 500 (q,tcol) tasks ------------
  for (int task = tid; task < 500; task += TPB) {
    const int q = task / 100;
    const int tcol = task - q * 100;
    const float* f0 = sm + OFF_F2V + (3 * q) * 104;
    float acc = 0.f;
    if (tcol < 50) {
      const int t = tcol;
      for (int a = 0; a <= 49 - t; ++a) {
        const int up = t + a;
        const float* wb = wcb_g + q * 303 + a * 3;
        acc = fmaf(Wv[0] * wb[0], f0[up], acc);
        acc = fmaf(Wv[1] * wb[1], f0[104 + up], acc);
        acc = fmaf(Wv[2] * wb[2], f0[208 + up], acc);
      }
    } else {
      const int tp = tcol;                           // t = 900+tp
      for (int d = 0; d <= tp - 50; ++d) {
        const int up = tp - d + 2;                   // +2: right-side layout shift
        const int a = 100 - d;
        const float* wb = wcb_g + q * 303 + a * 3;
        acc = fmaf(Wv[0] * wb[0], f0[up], acc);
        acc = fmaf(Wv[1] * wb[1], f0[104 + up], acc);
        acc = fmaf(Wv[2] * wb[2], f0[208 + up], acc);
      }
    }
    sm[OFF_PART + task] = acc;                       // PART[q*100+tcol]
  }
  __syncthreads();                                   // B9

  // ---------------- apply corrections + register-resident epilogue ----------
  if (tid < 250 && (t0 < 52 || t0 >= 948)) {
    #pragma unroll
    for (int j = 0; j < 4; ++j) {
      const int t = t0 + j;
      if (t < 50) {
        float c = 0.f;
        #pragma unroll
        for (int q = 0; q < 5; ++q) c += sm[OFF_PART + q * 100 + t];
        res[j] -= c;
      } else if (t >= 950) {
        const int tc = t - 900;
        float c = 0.f;
        #pragma unroll
        for (int q = 0; q < 5; ++q) c += sm[OFF_PART + q * 100 + tc];
        res[j] -= c;
      }
    }
  }
  float sp[4];
  float lm = -INFINITY;
  if (tid < 250) {
    #pragma unroll
    for (int j = 0; j < 4; ++j) {
      const float z = res[j];
      sp[j] = fmaxf(z, 0.f) + log1pf(expf(-fabsf(z)));   // stable softplus
      lm = fmaxf(lm, sp[j]);
    }
  }
  const float amax = blk_red_max(lm, red) + 1e-10f;
  float v4[4];
  float lm2 = -INFINITY;
  if (tid < 250) {
    const float4 mv = ld4(mask_g + (size_t)b * LW + t0);
    const float* mj = (const float*)&mv;
    const float ia = 1e4f / amax;
    #pragma unroll
    for (int j = 0; j < 4; ++j) {
      v4[j] = (sp[j] * ia) * mj[j];
      lm2 = fmaxf(lm2, v4[j]);
    }
  }
  const float m2 = blk_red_max(lm2, red);
  float ls = 0.f;
  float e4[4];
  if (tid < 250) {
    #pragma unroll
    for (int j = 0; j < 4; ++j) {
      e4[j] = expf(v4[j] - m2);
      ls += e4[j];
    }
  }
  const float S2 = blk_red_sum(ls, red);
  if (tid < 250) {
    const float invs = 1.f / S2;
    float4 st = { e4[0] * invs, e4[1] * invs, e4[2] * invs, e4[3] * invs };
    *(float4*)(out_g + (size_t)b * LW + t0) = st;
  }
}

extern "C" void kernel_launch(void* const* d_in, const int* in_sizes, int n_in,
                              void* d_out, int out_size, void* d_ws, size_t ws_size,
                              hipStream_t stream) {
  (void)n_in; (void)ws_size; (void)out_size;
  const float* wf   = (const float*)d_in[0];
  const float* mask = (const float*)d_in[1];
  const float* spe  = (const float*)d_in[2];
  const float* wca  = (const float*)d_in[3];
  const float* wx   = (const float*)d_in[4];
  const float* wdv  = (const float*)d_in[5];
  const float* wrl  = (const float*)d_in[6];
  const float* wsub = (const float*)d_in[7];
  const float* wcb  = (const float*)d_in[8];
  const float* wp   = (const float*)d_in[9];
  float* P = (float*)d_ws;                       // 1091 floats
  const int B = in_sizes[0] / LW;
  hipLaunchKernelGGL(prep_kernel, dim3(5), dim3(TPB), 0, stream, wsub, wcb, wca, spe, P);
  hipLaunchKernelGGL(spot_kernel, dim3(B), dim3(TPB), 0, stream,
                     wf, mask, spe, wca, wx, wdv, wrl, wsub, wcb, wp, P, (float*)d_out);
}

// Round 5
// 273.364 us; speedup vs baseline: 1.2320x; 1.0640x over previous
//
#include <hip/hip_runtime.h>
#include <math.h>

#define TPB 256
#define LW  1000
#define CSTR 1124   // f1e per-channel stride (1000 + 2*60 halo + 4 pad)

// ---- LDS layout (float offsets) ----
#define OFF_WFE   0        // 1120: wf reflect-ext, orig [-100,1020), core at +100
#define OFF_CUME  1120     // 1120: cumsum reflect-ext, core at +100
#define OFF_DSE   2240     // 1120: div_x_smd reflect-ext, core at +100
#define OFF_F1E   3360     // 3372 (+pad): features1_norm, core at +60, stride 1124
#define OFF_SCAND 3360     // alias: 512 floats = 256 doubles (wf fp64 scan)
#define OFF_C     3872     // alias: 1000 floats (d1 cumsum)
#define OFF_RED   6740     // 8 reduction scratch
#define SMEM_F    6748     // 26,992 B -> 6 blocks/CU
// phase-2 aliases of [0,3360) (staging dead after fused conv):
#define OFF_KC    0        // 372 composed kernel
#define OFF_WS2   376      // 1080 = 15*3 rows, stride 24 (21 used)
#define OFF_F2V   1456     // 1560 = 15*104: phantom f2; left at [0,50), right at [52,102)
#define OFF_PART  0        // 500 (alias KC/WS2 head; written after their last use)

__device__ __forceinline__ float4 ld4(const float* p) { return *(const float4*)p; }

__device__ __forceinline__ float blk_red_max(float v, float* red) {
  #pragma unroll
  for (int o = 32; o > 0; o >>= 1) v = fmaxf(v, __shfl_xor(v, o, 64));
  const int w = threadIdx.x >> 6;
  if ((threadIdx.x & 63) == 0) red[w] = v;
  __syncthreads();
  float r = fmaxf(fmaxf(red[0], red[1]), fmaxf(red[2], red[3]));
  __syncthreads();
  return r;
}

__device__ __forceinline__ float blk_red_sum(float v, float* red) {
  #pragma unroll
  for (int o = 32; o > 0; o >>= 1) v += __shfl_xor(v, o, 64);
  const int w = threadIdx.x >> 6;
  if ((threadIdx.x & 63) == 0) red[w] = v;
  __syncthreads();
  float r = red[0] + red[1] + red[2] + red[3];
  __syncthreads();
  return r;
}

__device__ __forceinline__ int refl(int j) {
  return j < 0 ? -j : (j >= LW ? 2 * LW - 2 - j : j);
}

// phantom-f2 inner: 21-tap conv, 4 outputs, sliding b128 window.
// OFF0 is the compile-time misalignment (0 for left side, 2 for right side).
template<int OFF0>
__device__ __forceinline__ void f2v_accum(const float* xr, const float* wr, float acc[4]) {
  float xw[12];
  *(float4*)xw       = ld4(xr);
  *(float4*)(xw + 4) = ld4(xr + 4);
  *(float4*)(xw + 8) = ld4(xr + 8);
  #pragma unroll
  for (int jb = 0; jb < 20; jb += 4) {
    float4 w4 = ld4(wr + jb);
    const float wv[4] = {w4.x, w4.y, w4.z, w4.w};
    #pragma unroll
    for (int kk = 0; kk < 4; ++kk)
      #pragma unroll
      for (int o = 0; o < 4; ++o)
        acc[o] = fmaf(wv[kk], xw[OFF0 + kk + o], acc[o]);
    #pragma unroll
    for (int j = 0; j < 8; ++j) xw[j] = xw[j + 4];
    *(float4*)(xw + 8) = ld4(xr + jb + 12);
  }
  const float w20 = wr[20];
  #pragma unroll
  for (int o = 0; o < 4; ++o) acc[o] = fmaf(w20, xw[OFF0 + o], acc[o]);
}

// P[m][cin][k] = sum_q conv(wcb[q,:,m], wsub[3q+m][cin])[k], k in [0,121)
// P[1089] = sum(wca); P[1090] = max(SPE); P[1091+k] = wca[k]-sum(wca)*wrl[k]
extern "C" __global__ void prep_kernel(const float* __restrict__ wsub_g,
                                       const float* __restrict__ wcb_g,
                                       const float* __restrict__ wca_g,
                                       const float* __restrict__ spe_g,
                                       const float* __restrict__ wrl_g,
                                       float* __restrict__ P) {
  __shared__ float sred[4];
  const int task = blockIdx.x * blockDim.x + threadIdx.x;
  if (task < 1089) {
    const int m = task / 363;
    const int r = task - m * 363;
    const int cin = r / 121;
    const int k = r - cin * 121;
    float acc = 0.f;
    for (int q = 0; q < 5; ++q) {
      const int ch = 3 * q + m;
      const float* ws = wsub_g + (ch * 3 + cin) * 21;
      #pragma unroll
      for (int j = 0; j < 21; ++j) {
        const int a = k - j;
        if (a >= 0 && a <= 100) acc = fmaf(ws[j], wcb_g[q * 303 + a * 3 + m], acc);
      }
    }
    P[task] = acc;
  } else if (task == 1089) {
    float s = 0.f;
    for (int k = 0; k < 121; ++k) s += wca_g[k];
    P[1089] = s;
  }
  if (blockIdx.x == 4) {   // SPE max
    float mx = -INFINITY;
    for (int t = threadIdx.x; t < LW; t += TPB) mx = fmaxf(mx, spe_g[t]);
    #pragma unroll
    for (int o = 32; o > 0; o >>= 1) mx = fmaxf(mx, __shfl_xor(mx, o, 64));
    if ((threadIdx.x & 63) == 0) sred[threadIdx.x >> 6] = mx;
    __syncthreads();
    if (threadIdx.x == 0)
      P[1090] = fmaxf(fmaxf(sred[0], sred[1]), fmaxf(sred[2], sred[3]));
    if (threadIdx.x < 121) {  // composed cum kernel: wca - sum(wca)*wrl (wrl 0-ext)
      const int k = threadIdx.x;
      float s = 0.f;
      for (int j = 0; j < 121; ++j) s += wca_g[j];
      const float w = (k < 101) ? wrl_g[k] : 0.f;
      P[1091 + k] = wca_g[k] - s * w;
    }
  }
}

extern "C" __global__ void __launch_bounds__(TPB, 6)
spot_kernel(const float* __restrict__ wf_g,  const float* __restrict__ mask_g,
            const float* __restrict__ spe_g, const float* __restrict__ wca_g,
            const float* __restrict__ wx_g,  const float* __restrict__ wdv_g,
            const float* __restrict__ wrl_g, const float* __restrict__ wsub_g,
            const float* __restrict__ wcb_g, const float* __restrict__ wp_g,
            const float* __restrict__ P_g,   float* __restrict__ out_g)
{
  __shared__ __align__(16) float sm[SMEM_F];
  const int tid = threadIdx.x;
  const int b = blockIdx.x;
  const float* wf = wf_g + (size_t)b * LW;
  float* red = sm + OFF_RED;
  const int t0 = 4 * tid;

  // ---------------- phase 0: staging, maxima, wf fp64 scan partials ----------
  for (int i = tid; i < 1120; i += TPB) sm[OFF_WFE + i] = wf[refl(i - 100)];
  double* scand = (double*)(sm + OFF_SCAND);
  double l0 = 0, l1 = 0, l2 = 0, l3 = 0;
  float hmx = -INFINITY;
  if (tid < 250) {
    float4 wv4 = ld4(wf + t0);
    hmx = fmaxf(fmaxf(wv4.x, wv4.y), fmaxf(wv4.z, wv4.w));
    l0 = (double)wv4.x;
    l1 = l0 + (double)wv4.y;
    l2 = l1 + (double)wv4.z;
    l3 = l2 + (double)wv4.w;
  }
  scand[tid] = l3;
  hmx = blk_red_max(hmx, red);   // barriers publish wfe/scand

  // per-sample 3-way mixing weights W
  const float smx = P_g[1090];
  const float h = hmx / smx;
  float a0 = -fmaxf(h - wp_g[0], 0.f);
  float a1 = -fmaxf(h - wp_g[1], 0.f);
  float a2 = -fmaxf(h - wp_g[2], 0.f);
  float am = fmaxf(a0, fmaxf(a1, a2));
  float e0 = expf(a0 - am), e1 = expf(a1 - am), e2 = expf(a2 - am);
  float es = e0 + e1 + e2;
  float Wv[3] = { e0 / es, e1 / es, e2 / es };

  // ---------------- wf cumsum: fp64 block scan ----------------
  if (tid < 64) {
    double s0 = scand[4 * tid], s1 = scand[4 * tid + 1];
    double s2 = scand[4 * tid + 2], s3 = scand[4 * tid + 3];
    double tot = s0 + s1 + s2 + s3;
    double inc = tot;
    #pragma unroll
    for (int o = 1; o < 64; o <<= 1) {
      double n = __shfl_up(inc, o, 64);
      if ((tid & 63) >= o) inc += n;
    }
    double ex = inc - tot;
    scand[4 * tid]     = ex;
    scand[4 * tid + 1] = ex + s0;
    scand[4 * tid + 2] = ex + s0 + s1;
    scand[4 * tid + 3] = ex + s0 + s1 + s2;
  }
  __syncthreads();                                   // B1
  if (tid < 250) {
    double base = scand[tid];
    float4 cv = { (float)(base + l0), (float)(base + l1),
                  (float)(base + l2), (float)(base + l3) };
    *(float4*)(sm + OFF_CUME + 100 + t0) = cv;
  }
  // d1 (9-tap derivative, zero-padded) in registers + fp32 scan partials
  const float dker[9] = {1.f/280.f, -4.f/105.f, 0.2f, -0.8f, 0.f, 0.8f, -0.2f, 4.f/105.f, -1.f/280.f};
  float dv0 = 0, dv1 = 0, dv2 = 0, dv3 = 0;
  if (tid >= 1 && tid <= 248) {          // safe interior: orig window [t0-4, t0+7]
    float xw[12];
    const float* xr = sm + OFF_WFE + t0 + 96;
    *(float4*)xw = ld4(xr); *(float4*)(xw+4) = ld4(xr+4); *(float4*)(xw+8) = ld4(xr+8);
    float d[4];
    #pragma unroll
    for (int j = 0; j < 4; ++j) {
      float a = 0.f;
      #pragma unroll
      for (int k = 0; k < 9; ++k) {
        if (k == 4) continue;
        a = fmaf(dker[k], xw[j + k], a);
      }
      d[j] = a;
    }
    dv0 = d[0]; dv1 = d[1]; dv2 = d[2]; dv3 = d[3];
  } else if (tid == 0 || tid == 249) {   // edges: zero-padded scalar path
    float d[4];
    #pragma unroll
    for (int j = 0; j < 4; ++j) {
      float a = 0.f;
      for (int k = 0; k < 9; ++k) {
        if (k == 4) continue;
        const int o = t0 + j - 4 + k;
        if (o >= 0 && o < LW) a = fmaf(dker[k], sm[OFF_WFE + 100 + o], a);
      }
      d[j] = a;
    }
    dv0 = d[0]; dv1 = d[1]; dv2 = d[2]; dv3 = d[3];
  }
  // fp32 scan of d1
  {
    const float s0 = dv0, s1 = s0 + dv1, s2 = s1 + dv2, s3 = s2 + dv3;
    float inc = s3;
    const int lane = tid & 63;
    #pragma unroll
    for (int o = 1; o < 64; o <<= 1) {
      float n = __shfl_up(inc, o, 64);
      if (lane >= o) inc += n;
    }
    float* redw = red + 4;
    if (lane == 63) redw[tid >> 6] = inc;
    __syncthreads();                                 // B2 (publishes CUME core too)
    float base = 0.f;
    for (int w = 0; w < (tid >> 6); ++w) base += redw[w];
    if (tid < 250) {
      const float ex = base + inc - s3;
      float4 cv = { ex + s0, ex + s1, ex + s2, ex + s3 };
      *(float4*)(sm + OFF_C + t0) = cv;
    }
  }
  __syncthreads();                                   // B3
  // dse core = (C[t+25]-C[t-26])/51 ; cume halos
  for (int t = tid; t < LW; t += TPB) {
    const float hi = sm[OFF_C + (t + 25 > 999 ? 999 : t + 25)];
    const float lo = (t >= 26) ? sm[OFF_C + t - 26] : 0.f;
    sm[OFF_DSE + 100 + t] = (hi - lo) * (1.f / 51.f);
  }
  for (int i = tid; i < 120; i += TPB) {
    if (i < 100) sm[OFF_CUME + i] = sm[OFF_CUME + 200 - i];
    else         sm[OFF_CUME + 1000 + i] = sm[OFF_CUME + 2198 - (1000 + i)];
  }
  __syncthreads();                                   // B4
  for (int i = tid; i < 120; i += TPB) {
    if (i < 100) sm[OFF_DSE + i] = sm[OFF_DSE + 200 - i];
    else         sm[OFF_DSE + 1000 + i] = sm[OFF_DSE + 2198 - (1000 + i)];
  }
  __syncthreads();                                   // B5

  // ---------------- fused 121-tap reflect convs -> features1 ----------------
  // (R0 loop skeleton preserved; aB stream deleted, weights = precomposed kcb)
  float lsC = 0.f, lsX = 0.f, lsD = 0.f;
  if (tid < 250) {
    const float* ce = sm + OFF_CUME + t0;
    const float* we = sm + OFF_WFE + t0;
    const float* de = sm + OFF_DSE + t0;
    const float* kcbP = P_g + 1091;                  // wca - sum(wca)*wrl (0-ext)
    float cw_[8], ww_[8], dw_[8];
    *(float4*)cw_ = ld4(ce); *(float4*)(cw_ + 4) = ld4(ce + 4);
    *(float4*)ww_ = ld4(we); *(float4*)(ww_ + 4) = ld4(we + 4);
    *(float4*)dw_ = ld4(de); *(float4*)(dw_ + 4) = ld4(de + 4);
    float aC[4] = {0,0,0,0}, aX[4] = {0,0,0,0}, aD[4] = {0,0,0,0};
    for (int g = 0; g < 100; g += 4) {               // taps 0..99
      #pragma unroll
      for (int kk = 0; kk < 4; ++kk) {
        const int k = g + kk;
        const float wa = kcbP[k], wxk = wx_g[k], wdk = wdv_g[k];
        #pragma unroll
        for (int j = 0; j < 4; ++j) {
          aC[j] = fmaf(wa,  cw_[kk + j], aC[j]);
          aX[j] = fmaf(wxk, ww_[kk + j], aX[j]);
          aD[j] = fmaf(wdk, dw_[kk + j], aD[j]);
        }
      }
      #pragma unroll
      for (int j = 0; j < 4; ++j) { cw_[j] = cw_[j+4]; ww_[j] = ww_[j+4]; dw_[j] = dw_[j+4]; }
      *(float4*)(cw_ + 4) = ld4(ce + g + 8);
      *(float4*)(ww_ + 4) = ld4(we + g + 8);
      *(float4*)(dw_ + 4) = ld4(de + g + 8);
    }
    for (int g = 100; g < 116; g += 4) {             // taps 100..115
      #pragma unroll
      for (int kk = 0; kk < 4; ++kk) {
        const int k = g + kk;
        const float wa = kcbP[k], wxk = wx_g[k], wdk = wdv_g[k];
        #pragma unroll
        for (int j = 0; j < 4; ++j) {
          aC[j] = fmaf(wa,  cw_[kk + j], aC[j]);
          aX[j] = fmaf(wxk, ww_[kk + j], aX[j]);
          aD[j] = fmaf(wdk, dw_[kk + j], aD[j]);
        }
      }
      #pragma unroll
      for (int j = 0; j < 4; ++j) { cw_[j] = cw_[j+4]; ww_[j] = ww_[j+4]; dw_[j] = dw_[j+4]; }
      *(float4*)(cw_ + 4) = ld4(ce + g + 8);
      *(float4*)(ww_ + 4) = ld4(we + g + 8);
      *(float4*)(dw_ + 4) = ld4(de + g + 8);
    }
    #pragma unroll
    for (int kk = 0; kk < 5; ++kk) {                 // taps 116..120 from window
      const int k = 116 + kk;
      const float wa = kcbP[k], wxk = wx_g[k], wdk = wdv_g[k];
      #pragma unroll
      for (int j = 0; j < 4; ++j) {
        aC[j] = fmaf(wa,  cw_[kk + j], aC[j]);
        aX[j] = fmaf(wxk, ww_[kk + j], aX[j]);
        aD[j] = fmaf(wdk, dw_[kk + j], aD[j]);
      }
    }
    float4 vC, vX, vD;
    float* pC = (float*)&vC; float* pX = (float*)&vX; float* pD = (float*)&vD;
    #pragma unroll
    for (int j = 0; j < 4; ++j) {
      float fc = fmaxf(aC[j], 0.f);
      float fx = fmaxf(aX[j], 0.f);
      float fd = fmaxf(aD[j], 0.f);
      pC[j] = fc; pX[j] = fx; pD[j] = fd;
      lsC += fc; lsX += fx; lsD += fd;
    }
    *(float4*)(sm + OFF_F1E + 0 * CSTR + 60 + t0) = vC;
    *(float4*)(sm + OFF_F1E + 1 * CSTR + 60 + t0) = vX;
    *(float4*)(sm + OFF_F1E + 2 * CSTR + 60 + t0) = vD;
  }
  const float SC = blk_red_sum(lsC, red) + 1e-10f;   // barriers publish f1
  const float SX = blk_red_sum(lsX, red) + 1e-10f;
  const float SD = blk_red_sum(lsD, red) + 1e-10f;
  {
    const float iC = 1.f / SC, iX = 1.f / SX, iD = 1.f / SD;
    for (int t = tid; t < LW; t += TPB) {
      sm[OFF_F1E + 0 * CSTR + 60 + t] *= iC;
      sm[OFF_F1E + 1 * CSTR + 60 + t] *= iX;
      sm[OFF_F1E + 2 * CSTR + 60 + t] *= iD;
    }
  }
  __syncthreads();                                   // B6

  // ---------------- f1 halos(60) + Kc + w_sub stage (staging dead) ----------
  for (int i = tid; i < 360; i += TPB) {
    const int c = i / 120, j = i - c * 120;
    const int dst = (j < 60) ? j : (1000 + j);          // right: 1060..1119
    const int src = (j < 60) ? (120 - j) : (1118 - j);
    sm[OFF_F1E + c * CSTR + dst] = sm[OFF_F1E + c * CSTR + src];
  }
  for (int i = tid; i < 363; i += TPB) {
    const int cin = i / 121, k = i - cin * 121;
    const float* Pp = P_g + cin * 121 + k;
    sm[OFF_KC + cin * 124 + k] =
        fmaf(Wv[0], Pp[0], fmaf(Wv[1], Pp[363], Wv[2] * Pp[726]));
  }
  for (int i = tid; i < 1080; i += TPB) {
    const int row = i / 24, k = i - row * 24;
    sm[OFF_WS2 + i] = (k < 21) ? wsub_g[row * 21 + k] : 0.f;
  }
  __syncthreads();                                   // B7

  // ---------------- composed 3x121 conv (regs) + vectorized phantom f2 ------
  float res[4] = {0, 0, 0, 0};
  if (tid < 250) {
    #pragma unroll
    for (int cin = 0; cin < 3; ++cin) {
      const float* xr = sm + OFF_F1E + cin * CSTR + t0;
      const float* kc = sm + OFF_KC + cin * 124;
      float xw[8];
      *(float4*)xw = ld4(xr); *(float4*)(xw + 4) = ld4(xr + 4);
      for (int g = 0; g < 120; g += 4) {
        float4 kw = ld4(kc + g);                     // LDS broadcast b128
        const float wv[4] = {kw.x, kw.y, kw.z, kw.w};
        #pragma unroll
        for (int kk = 0; kk < 4; ++kk)
          #pragma unroll
          for (int j = 0; j < 4; ++j) res[j] = fmaf(wv[kk], xw[kk + j], res[j]);
        #pragma unroll
        for (int j = 0; j < 4; ++j) xw[j] = xw[j + 4];
        *(float4*)(xw + 4) = ld4(xr + g + 8);
      }
      const float w120 = kc[120];
      #pragma unroll
      for (int j = 0; j < 4; ++j) res[j] = fmaf(w120, xw[j], res[j]);
    }
  }
  // phantom f2: 390 tasks (left 195, right 195), 4 outputs each
  for (int task = tid; task < 390; task += TPB) {
    const int side = (task >= 195) ? 1 : 0;
    const int r = task - 195 * side;
    const int ch = r / 13;
    const int gl = r - 13 * ch;
    float acc[4] = {0, 0, 0, 0};
    const float* wrb = sm + OFF_WS2 + ch * 72;
    if (side == 0) {
      const int xb = 4 * gl;
      #pragma unroll
      for (int cin = 0; cin < 3; ++cin)
        f2v_accum<0>(sm + OFF_F1E + cin * CSTR + xb, wrb + cin * 24, acc);
    } else {
      const int xb = 1048 + 4 * gl;
      #pragma unroll
      for (int cin = 0; cin < 3; ++cin)
        f2v_accum<2>(sm + OFF_F1E + cin * CSTR + xb, wrb + cin * 24, acc);
    }
    const int dst = OFF_F2V + ch * 104 + side * 52 + 4 * gl;
    if (gl < 12) {
      float4 st = {acc[0], acc[1], acc[2], acc[3]};
      *(float4*)(sm + dst) = st;
    } else {
      sm[dst] = acc[0]; sm[dst + 1] = acc[1];
    }
  }
  __syncthreads();                                   // B8

  // ---------------- edge-correction partials: 500 (q,tcol) tasks ------------
  for (int task = tid; task < 500; task += TPB) {
    const int q = task / 100;
    const int tcol = task - q * 100;
    const float* f0 = sm + OFF_F2V + (3 * q) * 104;
    float acc = 0.f;
    if (tcol < 50) {
      const int t = tcol;
      for (int a = 0; a <= 49 - t; ++a) {
        const int up = t + a;
        const float* wb = wcb_g + q * 303 + a * 3;
        acc = fmaf(Wv[0] * wb[0], f0[up], acc);
        acc = fmaf(Wv[1] * wb[1], f0[104 + up], acc);
        acc = fmaf(Wv[2] * wb[2], f0[208 + up], acc);
      }
    } else {
      const int tp = tcol;                           // t = 900+tp
      for (int d = 0; d <= tp - 50; ++d) {
        const int up = tp - d + 2;                   // +2: right-side layout shift
        const int a = 100 - d;
        const float* wb = wcb_g + q * 303 + a * 3;
        acc = fmaf(Wv[0] * wb[0], f0[up], acc);
        acc = fmaf(Wv[1] * wb[1], f0[104 + up], acc);
        acc = fmaf(Wv[2] * wb[2], f0[208 + up], acc);
      }
    }
    sm[OFF_PART + task] = acc;                       // PART[q*100+tcol]
  }
  __syncthreads();                                   // B9

  // ---------------- apply corrections + register-resident epilogue ----------
  if (tid < 250 && (t0 < 52 || t0 >= 948)) {
    #pragma unroll
    for (int j = 0; j < 4; ++j) {
      const int t = t0 + j;
      if (t < 50) {
        float c = 0.f;
        #pragma unroll
        for (int q = 0; q < 5; ++q) c += sm[OFF_PART + q * 100 + t];
        res[j] -= c;
      } else if (t >= 950) {
        const int tc = t - 900;
        float c = 0.f;
        #pragma unroll
        for (int q = 0; q < 5; ++q) c += sm[OFF_PART + q * 100 + tc];
        res[j] -= c;
      }
    }
  }
  float sp[4];
  float lm = -INFINITY;
  if (tid < 250) {
    #pragma unroll
    for (int j = 0; j < 4; ++j) {
      const float z = res[j];
      sp[j] = fmaxf(z, 0.f) + log1pf(expf(-fabsf(z)));   // stable softplus
      lm = fmaxf(lm, sp[j]);
    }
  }
  const float amax = blk_red_max(lm, red) + 1e-10f;
  float v4[4];
  float lm2 = -INFINITY;
  if (tid < 250) {
    const float4 mv = ld4(mask_g + (size_t)b * LW + t0);
    const float* mj = (const float*)&mv;
    const float ia = 1e4f / amax;
    #pragma unroll
    for (int j = 0; j < 4; ++j) {
      v4[j] = (sp[j] * ia) * mj[j];
      lm2 = fmaxf(lm2, v4[j]);
    }
  }
  const float m2 = blk_red_max(lm2, red);
  float ls = 0.f;
  float e4[4];
  if (tid < 250) {
    #pragma unroll
    for (int j = 0; j < 4; ++j) {
      e4[j] = expf(v4[j] - m2);
      ls += e4[j];
    }
  }
  const float S2 = blk_red_sum(ls, red);
  if (tid < 250) {
    const float invs = 1.f / S2;
    float4 st = { e4[0] * invs, e4[1] * invs, e4[2] * invs, e4[3] * invs };
    *(float4*)(out_g + (size_t)b * LW + t0) = st;
  }
}

extern "C" void kernel_launch(void* const* d_in, const int* in_sizes, int n_in,
                              void* d_out, int out_size, void* d_ws, size_t ws_size,
                              hipStream_t stream) {
  (void)n_in; (void)ws_size; (void)out_size;
  const float* wf   = (const float*)d_in[0];
  const float* mask = (const float*)d_in[1];
  const float* spe  = (const float*)d_in[2];
  const float* wca  = (const float*)d_in[3];
  const float* wx   = (const float*)d_in[4];
  const float* wdv  = (const float*)d_in[5];
  const float* wrl  = (const float*)d_in[6];
  const float* wsub = (const float*)d_in[7];
  const float* wcb  = (const float*)d_in[8];
  const float* wp   = (const float*)d_in[9];
  float* P = (float*)d_ws;                       // 1212 floats
  const int B = in_sizes[0] / LW;
  hipLaunchKernelGGL(prep_kernel, dim3(5), dim3(TPB), 0, stream, wsub, wcb, wca, spe, wrl, P);
  hipLaunchKernelGGL(spot_kernel, dim3(B), dim3(TPB), 0, stream,
                     wf, mask, spe, wca, wx, wdv, wrl, wsub, wcb, wp, P, (float*)d_out);
}